// Round 8
// baseline (402.973 us; speedup 1.0000x reference)
//
#include <hip/hip_runtime.h>
#include <math.h>

#define EPS 1e-5f

typedef float f32x4v __attribute__((ext_vector_type(4)));
typedef short s16x8  __attribute__((ext_vector_type(8)));

__device__ __forceinline__ float elu_f(float x) { return x > 0.f ? x : expm1f(x); }
__device__ __forceinline__ float blo(unsigned u) { return __uint_as_float(u << 16); }
__device__ __forceinline__ float bhi(unsigned u) { return __uint_as_float(u & 0xffff0000u); }
__device__ __forceinline__ unsigned f2b(float f) {  // RNE float->bf16
  unsigned u = __float_as_uint(f);
  unsigned r = ((u >> 16) & 1u) + 0x7fffu;
  return (u + r) >> 16;
}
__device__ __forceinline__ unsigned pack2(float a, float b) {
  return f2b(a) | (f2b(b) << 16);
}

// ---------------- merged: weight prep (blocks 0-319) + CSR p0 count/hist (blocks 320-447) ----------------
__global__ __launch_bounds__(256) void prep_csr0(const float* __restrict__ init_W,
    const float* __restrict__ mid_W, const float* __restrict__ er_W,
    const float* __restrict__ pr_W, const float* __restrict__ mid_g,
    const float* __restrict__ er_g, const float* __restrict__ pr_g,
    unsigned short* __restrict__ WT,
    const int* __restrict__ dst, int* __restrict__ partials, int Ecnt,
    const int* __restrict__ batch, float* __restrict__ counts, int Nn) {
  if (blockIdx.x < 320) {
    int grp = blockIdx.x >> 6;
    int i = (blockIdx.x & 63) * 256 + threadIdx.x;
    if (i >= 16384) return;
    int k = i >> 7, c = i & 127;
    if (grp == 0) {
      WT[c * 128 + k] = (unsigned short)f2b(init_W[k * 128 + c]);
      return;
    }
    const float* W; const float* g; unsigned short* Wd; unsigned short* W2;
    if (grp == 1)      { W = mid_W;             g = mid_g;       Wd = WT + 1 * 16384; W2 = WT + 2 * 16384; }
    else if (grp == 2) { W = mid_W + 256 * 128; g = mid_g + 128; Wd = WT + 3 * 16384; W2 = WT + 4 * 16384; }
    else if (grp == 3) { W = er_W;              g = er_g;        Wd = WT + 5 * 16384; W2 = WT + 6 * 16384; }
    else               { W = pr_W;              g = pr_g;        Wd = WT + 7 * 16384; W2 = WT + 8 * 16384; }
    float sg = (g[c] >= 0.f) ? 1.f : -1.f;
    float w1 = W[k * 128 + c];
    float w2 = W[(k + 128) * 128 + c];
    Wd[c * 128 + k] = (unsigned short)f2b((w1 - w2) * sg);
    W2[c * 128 + k] = (unsigned short)f2b(w2 * sg);
  } else {
    int b = blockIdx.x - 320;
    if (b < 64) {
      __shared__ int cnt[256];
      cnt[threadIdx.x] = 0;
      __syncthreads();
      int i0 = b * 256 + threadIdx.x, stride = 64 * 256;
      for (int e = i0; e < Ecnt; e += stride) atomicAdd(&cnt[(unsigned)dst[e] >> 8], 1);
      __syncthreads();
      partials[b * 256 + threadIdx.x] = cnt[threadIdx.x];
    } else {
      __shared__ float lc[64];
      if (threadIdx.x < 64) lc[threadIdx.x] = 0.f;
      __syncthreads();
      int i0 = (b - 64) * 256 + threadIdx.x, stride = 64 * 256;
      for (int n = i0; n < Nn; n += stride) atomicAdd(&lc[batch[n]], 1.f);
      __syncthreads();
      if (threadIdx.x < 64 && lc[threadIdx.x] != 0.f)
        atomicAdd(&counts[threadIdx.x * 16], lc[threadIdx.x]);
    }
  }
}

__global__ __launch_bounds__(256) void csr_p0_scan(const int* __restrict__ partials,
    int nblk, int* __restrict__ bucket_base, int* __restrict__ gcursor) {
  __shared__ int sc[256];
  int b = threadIdx.x;
  int s = 0;
  for (int k = 0; k < nblk; ++k) s += partials[k * 256 + b];
  sc[b] = s;
  __syncthreads();
  for (int off = 1; off < 256; off <<= 1) {
    int t = (b >= off) ? sc[b - off] : 0;
    __syncthreads();
    sc[b] += t;
    __syncthreads();
  }
  int excl = sc[b] - s;
  bucket_base[b] = excl;
  gcursor[b * 16] = excl;
  if (b == 255) bucket_base[256] = sc[255];
}

#define P1_CHUNK 4096
__device__ __forceinline__ void csr_p1_body(int bid, const int* __restrict__ src,
    const int* __restrict__ dst, int* __restrict__ gcursor,
    unsigned* __restrict__ binned, int Ecnt) {
  __shared__ unsigned stage[P1_CHUNK];
  __shared__ int cnt[256], lbase[256], gbase[256], lcur[256], sc[256];
  int tid = threadIdx.x;
  int e0 = bid * P1_CHUNK;
  int ecnt = Ecnt - e0; if (ecnt > P1_CHUNK) ecnt = P1_CHUNK;
  cnt[tid] = 0;
  __syncthreads();
  for (int i = tid; i < ecnt; i += 256) atomicAdd(&cnt[(unsigned)dst[e0 + i] >> 8], 1);
  __syncthreads();
  sc[tid] = cnt[tid];
  __syncthreads();
  for (int off = 1; off < 256; off <<= 1) {
    int t = (tid >= off) ? sc[tid - off] : 0;
    __syncthreads();
    sc[tid] += t;
    __syncthreads();
  }
  lbase[tid] = sc[tid] - cnt[tid];
  lcur[tid] = lbase[tid];
  gbase[tid] = (cnt[tid] > 0) ? atomicAdd(&gcursor[tid * 16], cnt[tid]) : 0;
  __syncthreads();
  for (int i = tid; i < ecnt; i += 256) {
    int d = dst[e0 + i], s = src[e0 + i];
    int bk = (unsigned)d >> 8;
    int p = atomicAdd(&lcur[bk], 1);
    stage[p] = ((unsigned)bk << 24) | ((unsigned)(d & 255) << 16) | (unsigned)s;
  }
  __syncthreads();
  for (int i = tid; i < ecnt; i += 256) {
    unsigned v = stage[i];
    int bk = v >> 24;
    binned[gbase[bk] + (i - lbase[bk])] = v;
  }
}

#define P2_CAP 12288
__device__ __forceinline__ void csr_p2_body(int bid, const unsigned* __restrict__ binned,
    const int* __restrict__ bucket_base, unsigned short* __restrict__ csr_src,
    int* __restrict__ deg, int* __restrict__ rowstart, int Nn) {
  __shared__ unsigned short stage[P2_CAP];
  __shared__ int cnt[256], lbase[256], lcur[256], sc[256];
  int b = bid, tid = threadIdx.x;
  int base = bucket_base[b];
  int bcnt = bucket_base[b + 1] - base;
  if (bcnt > P2_CAP) bcnt = P2_CAP;
  cnt[tid] = 0;
  __syncthreads();
  for (int i = tid; i < bcnt; i += 256) atomicAdd(&cnt[(binned[base + i] >> 16) & 255], 1);
  __syncthreads();
  sc[tid] = cnt[tid];
  __syncthreads();
  for (int off = 1; off < 256; off <<= 1) {
    int t = (tid >= off) ? sc[tid - off] : 0;
    __syncthreads();
    sc[tid] += t;
    __syncthreads();
  }
  lbase[tid] = sc[tid] - cnt[tid];
  lcur[tid] = lbase[tid];
  int node = b * 256 + tid;
  if (node < Nn) { deg[node] = cnt[tid]; rowstart[node] = base + lbase[tid]; }
  __syncthreads();
  for (int i = tid; i < bcnt; i += 256) {
    unsigned v = binned[base + i];
    int j = (v >> 16) & 255;
    int p = atomicAdd(&lcur[j], 1);
    stage[p] = (unsigned short)(v & 0xffffu);
  }
  __syncthreads();
  for (int i = tid; i < bcnt; i += 256) csr_src[base + i] = stage[i];
}

// ---------------- plain MFMA GEMM body (init layer: fp32 in, fused node stats) ----------------
template<int XF32, int NMAT, int STATS>
__device__ __forceinline__ void gemm_mfma_body(int bid, const void* __restrict__ Xv,
    const unsigned short* __restrict__ W0t, const unsigned short* __restrict__ W1t,
    const unsigned short* __restrict__ W2t, const unsigned short* __restrict__ W3t,
    unsigned short* __restrict__ Y0, unsigned short* __restrict__ Y1,
    unsigned short* __restrict__ Y2, unsigned short* __restrict__ Y3,
    float* __restrict__ stOut, int Nrows) {
  int tid = threadIdx.x, lane = tid & 63, wv = tid >> 6;
  int r0 = bid * 64;
  int rlo = lane & 15, kg = lane >> 4;
  s16x8 zf = {0, 0, 0, 0, 0, 0, 0, 0};
  s16x8 af[4][4];
#pragma unroll
  for (int rg = 0; rg < 4; ++rg) {
    int arow = r0 + rg * 16 + rlo;
    if (arow < Nrows) {
      if (XF32) {
        const float* xr = (const float*)Xv + (size_t)arow * 128 + kg * 8;
#pragma unroll
        for (int s2 = 0; s2 < 4; ++s2) {
          float4 a = *(const float4*)(xr + s2 * 32);
          float4 b = *(const float4*)(xr + s2 * 32 + 4);
          s16x8 t;
          t[0] = (short)f2b(a.x); t[1] = (short)f2b(a.y);
          t[2] = (short)f2b(a.z); t[3] = (short)f2b(a.w);
          t[4] = (short)f2b(b.x); t[5] = (short)f2b(b.y);
          t[6] = (short)f2b(b.z); t[7] = (short)f2b(b.w);
          af[rg][s2] = t;
        }
      } else {
        const unsigned short* xr = (const unsigned short*)Xv + (size_t)arow * 128 + kg * 8;
#pragma unroll
        for (int s2 = 0; s2 < 4; ++s2) af[rg][s2] = *(const s16x8*)(xr + s2 * 32);
      }
    } else {
#pragma unroll
      for (int s2 = 0; s2 < 4; ++s2) af[rg][s2] = zf;
    }
  }
  const unsigned short* Ws[4] = {W0t, W1t, W2t, W3t};
  unsigned short* Ys[4] = {Y0, Y1, Y2, Y3};
#pragma unroll
  for (int o = 0; o < NMAT; ++o) {
    const unsigned short* Wt = Ws[o];
    unsigned short* Y = Ys[o];
#pragma unroll
    for (int t = 0; t < 2; ++t) {
      int nt = wv * 2 + t;
      const unsigned short* wp = Wt + (size_t)(nt * 16 + rlo) * 128 + kg * 8;
      s16x8 wf[4];
#pragma unroll
      for (int s2 = 0; s2 < 4; ++s2) wf[s2] = *(const s16x8*)(wp + s2 * 32);
      f32x4v acc[4];
#pragma unroll
      for (int rg = 0; rg < 4; ++rg) acc[rg] = (f32x4v){0.f, 0.f, 0.f, 0.f};
#pragma unroll
      for (int s2 = 0; s2 < 4; ++s2)
#pragma unroll
        for (int rg = 0; rg < 4; ++rg)
          acc[rg] = __builtin_amdgcn_mfma_f32_16x16x32_bf16(wf[s2], af[rg][s2], acc[rg], 0, 0, 0);
      float ps0 = 0.f, ps1 = 0.f, ps2 = 0.f, ps3 = 0.f;
      float pq0 = 0.f, pq1 = 0.f, pq2 = 0.f, pq3 = 0.f;
#pragma unroll
      for (int rg = 0; rg < 4; ++rg) {
        int arow = r0 + rg * 16 + rlo;
        if (arow < Nrows) {
          uint2 ov;
          ov.x = pack2(acc[rg][0], acc[rg][1]);
          ov.y = pack2(acc[rg][2], acc[rg][3]);
          *(uint2*)(Y + (size_t)arow * 128 + nt * 16 + kg * 4) = ov;
          if (STATS) {
            float y0 = blo(ov.x), y1 = bhi(ov.x), y2 = blo(ov.y), y3 = bhi(ov.y);
            ps0 += y0; pq0 += y0 * y0;
            ps1 += y1; pq1 += y1 * y1;
            ps2 += y2; pq2 += y2 * y2;
            ps3 += y3; pq3 += y3 * y3;
          }
        }
      }
      if (STATS) {
#pragma unroll
        for (int off = 1; off < 16; off <<= 1) {
          ps0 += __shfl_xor(ps0, off); pq0 += __shfl_xor(pq0, off);
          ps1 += __shfl_xor(ps1, off); pq1 += __shfl_xor(pq1, off);
          ps2 += __shfl_xor(ps2, off); pq2 += __shfl_xor(pq2, off);
          ps3 += __shfl_xor(ps3, off); pq3 += __shfl_xor(pq3, off);
        }
        if (rlo == 0) {
          int col = nt * 16 + kg * 4;
          float* sb = stOut + (size_t)(bid & 15) * 256;
          atomicAdd(&sb[2 * col + 0], ps0); atomicAdd(&sb[2 * col + 1], pq0);
          atomicAdd(&sb[2 * (col + 1)], ps1); atomicAdd(&sb[2 * (col + 1) + 1], pq1);
          atomicAdd(&sb[2 * (col + 2)], ps2); atomicAdd(&sb[2 * (col + 2) + 1], pq2);
          atomicAdd(&sb[2 * (col + 3)], ps3); atomicAdd(&sb[2 * (col + 3) + 1], pq3);
        }
      }
    }
  }
}

// ---------------- activation-fused GEMM body: phase A (BN+act -> LDS, zP dot) ; phase B (MFMA) ----
template<int NMAT, int ACT>
__device__ __forceinline__ void gemm_act_body(int bid, const unsigned short* __restrict__ Xv,
    const unsigned short* __restrict__ W0t, const unsigned short* __restrict__ W1t,
    const unsigned short* __restrict__ W2t, const unsigned short* __restrict__ W3t,
    unsigned short* __restrict__ Y0, unsigned short* __restrict__ Y1,
    unsigned short* __restrict__ Y2, unsigned short* __restrict__ Y3,
    const float* __restrict__ stn, const float* __restrict__ g,
    const float* __restrict__ bt, const int* __restrict__ deg,
    const float* __restrict__ Wp, float* __restrict__ zP, float* __restrict__ stp,
    float invCnt, int Nrows) {
  __shared__ unsigned short hl[64][136];
  __shared__ float lsc[128], lsh[128], lw0[128], lw1[128];
  __shared__ float red[4][4];
  int tid = threadIdx.x, lane = tid & 63, wv = tid >> 6;
  int r0 = bid * 64;
  int rlo = lane & 15, kg = lane >> 4;
  if (tid < 128) {
    float sm = 0.f, sq = 0.f;
#pragma unroll
    for (int k = 0; k < 16; ++k) {
      sm += stn[k * 256 + 2 * tid];
      sq += stn[k * 256 + 2 * tid + 1];
    }
    float mean = sm * invCnt;
    float var = sq * invCnt - mean * mean;
    float sc = g[tid] * rsqrtf(var + EPS);
    float sh = bt[tid] - mean * sc;
    if (ACT == 2 && g[tid] < 0.f) sc = -sc;
    lsc[tid] = sc; lsh[tid] = sh;
    lw0[tid] = Wp[tid * 2]; lw1[tid] = Wp[tid * 2 + 1];
  }
  __syncthreads();
  {
    int row = tid >> 2, q = tid & 3;
    int arow = r0 + row;
    bool rok = arow < Nrows;
    int lrow = rok ? arow : 0;
    float live = 1.f;
    if (ACT == 2) live = (rok && deg[arow] > 0) ? 1.f : 0.f;
    else live = rok ? 1.f : 0.f;
    const uint4* xr = (const uint4*)(Xv + (size_t)lrow * 128 + q * 32);
    float dd0 = 0.f, dd1 = 0.f;
#pragma unroll
    for (int b = 0; b < 4; ++b) {
      uint4 v = xr[b];
      unsigned w[4] = {v.x, v.y, v.z, v.w};
      int cb = q * 32 + b * 8;
#pragma unroll
      for (int u = 0; u < 4; ++u) {
        int c = cb + 2 * u;
        float t0 = blo(w[u]) * lsc[c] + lsh[c];
        float t1 = bhi(w[u]) * lsc[c + 1] + lsh[c + 1];
        float y0, y1;
        if (ACT == 1) {
          y0 = 0.5f * t0 * (1.f + erff(t0 * 0.70710678118f));
          y1 = 0.5f * t1 * (1.f + erff(t1 * 0.70710678118f));
        } else {
          y0 = elu_f(t0); y1 = elu_f(t1);
        }
        y0 *= live; y1 *= live;
        *(unsigned*)&hl[row][c] = pack2(y0, y1);
        dd0 += y0 * lw0[c] + y1 * lw0[c + 1];
        dd1 += y0 * lw1[c] + y1 * lw1[c + 1];
      }
    }
    dd0 += __shfl_xor(dd0, 1); dd0 += __shfl_xor(dd0, 2);
    dd1 += __shfl_xor(dd1, 1); dd1 += __shfl_xor(dd1, 2);
    if (q == 0 && rok) {
      zP[(size_t)arow * 2] = dd0;
      zP[(size_t)arow * 2 + 1] = dd1;
    }
    float s0v = (q == 0 && rok) ? dd0 : 0.f;
    float s1v = (q == 0 && rok) ? dd1 : 0.f;
    float q0v = s0v * s0v, q1v = s1v * s1v;
#pragma unroll
    for (int off = 4; off < 64; off <<= 1) {
      s0v += __shfl_xor(s0v, off); s1v += __shfl_xor(s1v, off);
      q0v += __shfl_xor(q0v, off); q1v += __shfl_xor(q1v, off);
    }
    if (lane == 0) { red[wv][0] = s0v; red[wv][1] = s1v; red[wv][2] = q0v; red[wv][3] = q1v; }
  }
  __syncthreads();
  if (tid < 4) {
    float v = red[0][tid] + red[1][tid] + red[2][tid] + red[3][tid];
    atomicAdd(&stp[tid * 64], v);
  }
  s16x8 af[4][4];
#pragma unroll
  for (int rg = 0; rg < 4; ++rg)
#pragma unroll
    for (int s2 = 0; s2 < 4; ++s2)
      af[rg][s2] = *(const s16x8*)&hl[rg * 16 + rlo][kg * 8 + s2 * 32];
  const unsigned short* Ws[4] = {W0t, W1t, W2t, W3t};
  unsigned short* Ys[4] = {Y0, Y1, Y2, Y3};
#pragma unroll
  for (int o = 0; o < NMAT; ++o) {
    const unsigned short* Wt = Ws[o];
    unsigned short* Y = Ys[o];
#pragma unroll
    for (int t = 0; t < 2; ++t) {
      int nt = wv * 2 + t;
      const unsigned short* wp = Wt + (size_t)(nt * 16 + rlo) * 128 + kg * 8;
      s16x8 wf[4];
#pragma unroll
      for (int s2 = 0; s2 < 4; ++s2) wf[s2] = *(const s16x8*)(wp + s2 * 32);
      f32x4v acc[4];
#pragma unroll
      for (int rg = 0; rg < 4; ++rg) acc[rg] = (f32x4v){0.f, 0.f, 0.f, 0.f};
#pragma unroll
      for (int s2 = 0; s2 < 4; ++s2)
#pragma unroll
        for (int rg = 0; rg < 4; ++rg)
          acc[rg] = __builtin_amdgcn_mfma_f32_16x16x32_bf16(wf[s2], af[rg][s2], acc[rg], 0, 0, 0);
#pragma unroll
      for (int rg = 0; rg < 4; ++rg) {
        int arow = r0 + rg * 16 + rlo;
        if (arow < Nrows) {
          uint2 ov;
          ov.x = pack2(acc[rg][0], acc[rg][1]);
          ov.y = pack2(acc[rg][2], acc[rg][3]);
          *(uint2*)(Y + (size_t)arow * 128 + nt * 16 + kg * 4) = ov;
        }
      }
    }
  }
}

// standalone ACT-GEMM kernels (mid1, er/pr)
template<int NMAT, int ACT>
__global__ __launch_bounds__(256, 3) void gemm_act(const unsigned short* __restrict__ Xv,
    const unsigned short* __restrict__ W0t, const unsigned short* __restrict__ W1t,
    const unsigned short* __restrict__ W2t, const unsigned short* __restrict__ W3t,
    unsigned short* __restrict__ Y0, unsigned short* __restrict__ Y1,
    unsigned short* __restrict__ Y2, unsigned short* __restrict__ Y3,
    const float* __restrict__ stn, const float* __restrict__ g,
    const float* __restrict__ bt, const int* __restrict__ deg,
    const float* __restrict__ Wp, float* __restrict__ zP, float* __restrict__ stp,
    float invCnt, int Nrows) {
  gemm_act_body<NMAT, ACT>(blockIdx.x, Xv, W0t, W1t, W2t, W3t, Y0, Y1, Y2, Y3,
                           stn, g, bt, deg, Wp, zP, stp, invCnt, Nrows);
}

// merged: CSR p1 bin (blocks 0..p1b-1) + init GEMM (blocks p1b..)
__global__ __launch_bounds__(256, 3) void p1_initgemm(
    const int* __restrict__ src, const int* __restrict__ dst, int* __restrict__ gcursor,
    unsigned* __restrict__ binned, int Ecnt, int p1b,
    const void* __restrict__ Xv, const unsigned short* __restrict__ W0t,
    unsigned short* __restrict__ Y0, float* __restrict__ stOut, int Nrows) {
  if ((int)blockIdx.x < p1b) {
    csr_p1_body(blockIdx.x, src, dst, gcursor, binned, Ecnt);
  } else {
    gemm_mfma_body<1, 1, 1>(blockIdx.x - p1b, Xv, W0t, nullptr, nullptr, nullptr,
                            Y0, nullptr, nullptr, nullptr, stOut, Nrows);
  }
}

// merged: CSR p2 sort (blocks 0..nbuck-1) + mid0 ACT-GEMM (blocks nbuck..)
// Safe: ACT=1 path never reads deg (written here by p2).
__global__ __launch_bounds__(256, 3) void p2_act0(
    const unsigned* __restrict__ binned, const int* __restrict__ bucket_base,
    unsigned short* __restrict__ csr_src, int* __restrict__ deg,
    int* __restrict__ rowstart, int Nn, int nbuck,
    const unsigned short* __restrict__ Xv,
    const unsigned short* __restrict__ W0t, const unsigned short* __restrict__ W1t,
    unsigned short* __restrict__ Y0, unsigned short* __restrict__ Y1,
    const float* __restrict__ stn, const float* __restrict__ g,
    const float* __restrict__ bt, const float* __restrict__ Wp,
    float* __restrict__ zP, float* __restrict__ stp, float invCnt) {
  if ((int)blockIdx.x < nbuck) {
    csr_p2_body(blockIdx.x, binned, bucket_base, csr_src, deg, rowstart, Nn);
  } else {
    gemm_act_body<2, 1>(blockIdx.x - nbuck, Xv, W0t, W1t, nullptr, nullptr,
                        Y0, Y1, nullptr, nullptr, stn, g, bt, nullptr,
                        Wp, zP, stp, invCnt, Nn);
  }
}

// ---------------- conv pass: dst-term pullout (R1 algebra, R4 loop structure) + phase2 tail ----
// stpp format: [0]=sum0, [64]=sum1, [128]=ssq0, [192]=ssq1
__global__ __launch_bounds__(256, 8) void conv_pass(const unsigned short* __restrict__ A,
    const unsigned short* __restrict__ B, const unsigned short* __restrict__ csr_src,
    const int* __restrict__ rowstart, const int* __restrict__ deg,
    const float* __restrict__ g, unsigned short* __restrict__ Mx,
    float* __restrict__ st, int Nn, int convBlks,
    const float* __restrict__ zPp, const int* __restrict__ batch,
    const float* __restrict__ counts, const float* __restrict__ stpp,
    const float* __restrict__ g2, const float* __restrict__ bt2,
    float* __restrict__ out, float invN) {
  __shared__ float s_sum[128], s_ssq[128];
  int tid = threadIdx.x;
  if ((int)blockIdx.x >= convBlks) {
    __shared__ float lacc[128];
    if (tid < 128) lacc[tid] = 0.f;
    __syncthreads();
    float m0 = stpp[0] * invN, v0 = stpp[128] * invN - m0 * m0;
    float scale0 = g2[0] * rsqrtf(v0 + EPS), shift0 = bt2[0] - m0 * scale0;
    float m1 = stpp[64] * invN, v1 = stpp[192] * invN - m1 * m1;
    float scale1 = g2[1] * rsqrtf(v1 + EPS), shift1 = bt2[1] - m1 * scale1;
    int i0 = (blockIdx.x - convBlks) * 256 + tid;
    int stride = 32 * 256;
    for (int n = i0; n < Nn; n += stride) {
      int gi = batch[n];
      atomicAdd(&lacc[gi * 2], elu_f(zPp[n * 2] * scale0 + shift0));
      atomicAdd(&lacc[gi * 2 + 1], elu_f(zPp[n * 2 + 1] * scale1 + shift1));
    }
    __syncthreads();
    if (tid < 128) {
      int gi = tid >> 1, p = tid & 1;
      float v = lacc[tid];
      if (v != 0.f) atomicAdd(&out[gi * 2 + p], v / fmaxf(counts[gi * 16], 1.f));
    }
    return;
  }
  if (tid < 128) { s_sum[tid] = 0.f; s_ssq[tid] = 0.f; }
  __syncthreads();
  int lane = tid & 63;
  int wave = __builtin_amdgcn_readfirstlane((blockIdx.x << 2) + (tid >> 6));
  int wstride = convBlks << 2;
  int c0 = lane * 2;
  float sg0 = (g[c0] >= 0.f) ? 1.f : -1.f;
  float sg1 = (g[c0 + 1] >= 0.f) ? 1.f : -1.f;
  const unsigned* A32 = (const unsigned*)A;
  const unsigned* B32 = (const unsigned*)B;
  unsigned* M32 = (unsigned*)Mx;
  float rP0 = 0.f, rP1 = 0.f;   // sum dg*a
  float rQ0 = 0.f, rQ1 = 0.f;   // sum dg*a^2
  float rC0 = 0.f, rC1 = 0.f;   // sum a*T
  float rT0 = 0.f, rT1 = 0.f;   // sum T
  float rB0 = 0.f, rB1 = 0.f;   // sum b^2
  for (int n = wave; n < Nn; n += wstride) {
    int dg = deg[n];
    if (dg == 0) continue;
    int beg = rowstart[n];
    unsigned ua = A32[(size_t)n * 64 + lane];
    float a0 = blo(ua), a1 = bhi(ua);
    float T0 = 0.f, T1 = 0.f;
    float mx0 = -INFINITY, mx1 = -INFINITY;
    int e = beg, eend = beg + dg;
    for (; e + 8 <= eend; e += 8) {
      int idx[8];
#pragma unroll
      for (int q = 0; q < 8; ++q) idx[q] = csr_src[e + q];
      unsigned uu[8];
#pragma unroll
      for (int q = 0; q < 8; ++q) uu[q] = B32[(size_t)idx[q] * 64 + lane];
#pragma unroll
      for (int q = 0; q < 8; ++q) {
        float b0 = blo(uu[q]), b1 = bhi(uu[q]);
        T0 += b0; T1 += b1;
        rB0 += b0 * b0; rB1 += b1 * b1;
        mx0 = fmaxf(mx0, b0); mx1 = fmaxf(mx1, b1);
      }
    }
    for (; e + 2 <= eend; e += 2) {
      int ia = csr_src[e], ib = csr_src[e + 1];
      unsigned u0 = B32[(size_t)ia * 64 + lane];
      unsigned u1 = B32[(size_t)ib * 64 + lane];
      float b00 = blo(u0), b01 = bhi(u0);
      float b10 = blo(u1), b11 = bhi(u1);
      T0 += b00 + b10; T1 += b01 + b11;
      rB0 += b00 * b00 + b10 * b10; rB1 += b01 * b01 + b11 * b11;
      mx0 = fmaxf(mx0, fmaxf(b00, b10));
      mx1 = fmaxf(mx1, fmaxf(b01, b11));
    }
    if (e < eend) {
      unsigned u0 = B32[(size_t)csr_src[e] * 64 + lane];
      float b00 = blo(u0), b01 = bhi(u0);
      T0 += b00; T1 += b01;
      rB0 += b00 * b00; rB1 += b01 * b01;
      mx0 = fmaxf(mx0, b00); mx1 = fmaxf(mx1, b01);
    }
    float fdg = (float)dg;
    rP0 += fdg * a0; rP1 += fdg * a1;
    rQ0 += fdg * a0 * a0; rQ1 += fdg * a1 * a1;
    rC0 += a0 * T0; rC1 += a1 * T1;
    rT0 += T0; rT1 += T1;
    M32[(size_t)n * 64 + lane] = pack2(a0 + mx0, a1 + mx1);
  }
  atomicAdd(&s_sum[c0], (rP0 + rT0) * sg0);
  atomicAdd(&s_ssq[c0], rQ0 + 2.f * rC0 + rB0);
  atomicAdd(&s_sum[c0 + 1], (rP1 + rT1) * sg1);
  atomicAdd(&s_ssq[c0 + 1], rQ1 + 2.f * rC1 + rB1);
  __syncthreads();
  if (tid < 128) {
    float* sb = st + (size_t)(blockIdx.x & 15) * 256;
    atomicAdd(&sb[2 * tid], s_sum[tid]);
    atomicAdd(&sb[2 * tid + 1], s_ssq[tid]);
  }
}

// ---------------- DUAL conv pass: dst-term pullout, separate tables, + phase2 tail ----------------
__global__ __launch_bounds__(256, 8) void conv_pass_dual(
    const unsigned short* __restrict__ Aer, const unsigned short* __restrict__ Ber,
    const unsigned short* __restrict__ Apr, const unsigned short* __restrict__ Bpr,
    const unsigned short* __restrict__ csr_src,
    const int* __restrict__ rowstart, const int* __restrict__ deg,
    const float* __restrict__ g_er, const float* __restrict__ g_pr,
    unsigned short* __restrict__ Mer, unsigned short* __restrict__ Mpr,
    float* __restrict__ st_er, float* __restrict__ st_pr, int Nn, int convBlks,
    const float* __restrict__ zPp, const int* __restrict__ batch,
    const float* __restrict__ counts, const float* __restrict__ stpp,
    const float* __restrict__ g2, const float* __restrict__ bt2,
    float* __restrict__ out, float invN) {
  __shared__ float s_e[256], s_p[256];
  int tid = threadIdx.x;
  if ((int)blockIdx.x >= convBlks) {
    __shared__ float lacc[128];
    if (tid < 128) lacc[tid] = 0.f;
    __syncthreads();
    float m0 = stpp[0] * invN, v0 = stpp[128] * invN - m0 * m0;
    float scale0 = g2[0] * rsqrtf(v0 + EPS), shift0 = bt2[0] - m0 * scale0;
    float m1 = stpp[64] * invN, v1 = stpp[192] * invN - m1 * m1;
    float scale1 = g2[1] * rsqrtf(v1 + EPS), shift1 = bt2[1] - m1 * scale1;
    int i0 = (blockIdx.x - convBlks) * 256 + tid;
    int stride = 32 * 256;
    for (int n = i0; n < Nn; n += stride) {
      int gi = batch[n];
      atomicAdd(&lacc[gi * 2], elu_f(zPp[n * 2] * scale0 + shift0));
      atomicAdd(&lacc[gi * 2 + 1], elu_f(zPp[n * 2 + 1] * scale1 + shift1));
    }
    __syncthreads();
    if (tid < 128) {
      int gi = tid >> 1, p = tid & 1;
      float v = lacc[tid];
      if (v != 0.f) atomicAdd(&out[gi * 2 + p], v / fmaxf(counts[gi * 16], 1.f));
    }
    return;
  }
  s_e[tid] = 0.f; s_p[tid] = 0.f;
  __syncthreads();
  int lane = tid & 63;
  int wave = __builtin_amdgcn_readfirstlane((blockIdx.x << 2) + (tid >> 6));
  int wstride = convBlks << 2;
  int c0 = lane * 2;
  float sge0 = (g_er[c0] >= 0.f) ? 1.f : -1.f;
  float sge1 = (g_er[c0 + 1] >= 0.f) ? 1.f : -1.f;
  float sgp0 = (g_pr[c0] >= 0.f) ? 1.f : -1.f;
  float sgp1 = (g_pr[c0 + 1] >= 0.f) ? 1.f : -1.f;
  const unsigned* Ae32 = (const unsigned*)Aer;
  const unsigned* Be32 = (const unsigned*)Ber;
  const unsigned* Ap32 = (const unsigned*)Apr;
  const unsigned* Bp32 = (const unsigned*)Bpr;
  unsigned* Me32 = (unsigned*)Mer;
  unsigned* Mp32 = (unsigned*)Mpr;
  float rPe0 = 0.f, rPe1 = 0.f, rPp0 = 0.f, rPp1 = 0.f;
  float rQe0 = 0.f, rQe1 = 0.f, rQp0 = 0.f, rQp1 = 0.f;
  float rCe0 = 0.f, rCe1 = 0.f, rCp0 = 0.f, rCp1 = 0.f;
  float rTe0 = 0.f, rTe1 = 0.f, rTp0 = 0.f, rTp1 = 0.f;
  float rBe0 = 0.f, rBe1 = 0.f, rBp0 = 0.f, rBp1 = 0.f;
  for (int n = wave; n < Nn; n += wstride) {
    int dg = deg[n];
    if (dg == 0) continue;
    int beg = rowstart[n];
    unsigned uae = Ae32[(size_t)n * 64 + lane];
    unsigned uap = Ap32[(size_t)n * 64 + lane];
    float ae0 = blo(uae), ae1 = bhi(uae);
    float ap0 = blo(uap), ap1 = bhi(uap);
    float Te0 = 0.f, Te1 = 0.f, Tp0 = 0.f, Tp1 = 0.f;
    float mxe0 = -INFINITY, mxe1 = -INFINITY, mxp0 = -INFINITY, mxp1 = -INFINITY;
    int e = beg, eend = beg + dg;
    for (; e + 8 <= eend; e += 8) {
      int idx[8];
#pragma unroll
      for (int q = 0; q < 8; ++q) idx[q] = csr_src[e + q];
      unsigned ue[8], up[8];
#pragma unroll
      for (int q = 0; q < 8; ++q) ue[q] = Be32[(size_t)idx[q] * 64 + lane];
#pragma unroll
      for (int q = 0; q < 8; ++q) up[q] = Bp32[(size_t)idx[q] * 64 + lane];
#pragma unroll
      for (int q = 0; q < 8; ++q) {
        float be0 = blo(ue[q]), be1 = bhi(ue[q]);
        float bp0 = blo(up[q]), bp1 = bhi(up[q]);
        Te0 += be0; Te1 += be1; Tp0 += bp0; Tp1 += bp1;
        rBe0 += be0 * be0; rBe1 += be1 * be1;
        rBp0 += bp0 * bp0; rBp1 += bp1 * bp1;
        mxe0 = fmaxf(mxe0, be0); mxe1 = fmaxf(mxe1, be1);
        mxp0 = fmaxf(mxp0, bp0); mxp1 = fmaxf(mxp1, bp1);
      }
    }
    for (; e + 2 <= eend; e += 2) {
      int i0 = csr_src[e], i1 = csr_src[e + 1];
      unsigned ue0 = Be32[(size_t)i0 * 64 + lane];
      unsigned up0 = Bp32[(size_t)i0 * 64 + lane];
      unsigned ue1 = Be32[(size_t)i1 * 64 + lane];
      unsigned up1 = Bp32[(size_t)i1 * 64 + lane];
      float be00 = blo(ue0), be01 = bhi(ue0);
      float bp00 = blo(up0), bp01 = bhi(up0);
      float be10 = blo(ue1), be11 = bhi(ue1);
      float bp10 = blo(up1), bp11 = bhi(up1);
      Te0 += be00 + be10; Te1 += be01 + be11;
      Tp0 += bp00 + bp10; Tp1 += bp01 + bp11;
      rBe0 += be00 * be00 + be10 * be10; rBe1 += be01 * be01 + be11 * be11;
      rBp0 += bp00 * bp00 + bp10 * bp10; rBp1 += bp01 * bp01 + bp11 * bp11;
      mxe0 = fmaxf(mxe0, fmaxf(be00, be10)); mxe1 = fmaxf(mxe1, fmaxf(be01, be11));
      mxp0 = fmaxf(mxp0, fmaxf(bp00, bp10)); mxp1 = fmaxf(mxp1, fmaxf(bp01, bp11));
    }
    if (e < eend) {
      int i0 = csr_src[e];
      unsigned ue0 = Be32[(size_t)i0 * 64 + lane];
      unsigned up0 = Bp32[(size_t)i0 * 64 + lane];
      float be00 = blo(ue0), be01 = bhi(ue0);
      float bp00 = blo(up0), bp01 = bhi(up0);
      Te0 += be00; Te1 += be01; Tp0 += bp00; Tp1 += bp01;
      rBe0 += be00 * be00; rBe1 += be01 * be01;
      rBp0 += bp00 * bp00; rBp1 += bp01 * bp01;
      mxe0 = fmaxf(mxe0, be00); mxe1 = fmaxf(mxe1, be01);
      mxp0 = fmaxf(mxp0, bp00); mxp1 = fmaxf(mxp1, bp01);
    }
    float fdg = (float)dg;
    rPe0 += fdg * ae0; rPe1 += fdg * ae1;
    rPp0 += fdg * ap0; rPp1 += fdg * ap1;
    rQe0 += fdg * ae0 * ae0; rQe1 += fdg * ae1 * ae1;
    rQp0 += fdg * ap0 * ap0; rQp1 += fdg * ap1 * ap1;
    rCe0 += ae0 * Te0; rCe1 += ae1 * Te1;
    rCp0 += ap0 * Tp0; rCp1 += ap1 * Tp1;
    rTe0 += Te0; rTe1 += Te1; rTp0 += Tp0; rTp1 += Tp1;
    Me32[(size_t)n * 64 + lane] = pack2(ae0 + mxe0, ae1 + mxe1);
    Mp32[(size_t)n * 64 + lane] = pack2(ap0 + mxp0, ap1 + mxp1);
  }
  atomicAdd(&s_e[2 * c0], (rPe0 + rTe0) * sge0);
  atomicAdd(&s_e[2 * c0 + 1], rQe0 + 2.f * rCe0 + rBe0);
  atomicAdd(&s_e[2 * (c0 + 1)], (rPe1 + rTe1) * sge1);
  atomicAdd(&s_e[2 * (c0 + 1) + 1], rQe1 + 2.f * rCe1 + rBe1);
  atomicAdd(&s_p[2 * c0], (rPp0 + rTp0) * sgp0);
  atomicAdd(&s_p[2 * c0 + 1], rQp0 + 2.f * rCp0 + rBp0);
  atomicAdd(&s_p[2 * (c0 + 1)], (rPp1 + rTp1) * sgp1);
  atomicAdd(&s_p[2 * (c0 + 1) + 1], rQp1 + 2.f * rCp1 + rBp1);
  __syncthreads();
  {
    float* se = st_er + (size_t)(blockIdx.x & 15) * 256;
    float* sp = st_pr + (size_t)(blockIdx.x & 15) * 256;
    atomicAdd(&se[tid], s_e[tid]);
    atomicAdd(&sp[tid], s_p[tid]);
  }
}

// ---------------- DUAL fused post: er + pr in one pass (terminal) ----------------
__global__ __launch_bounds__(256) void fused_post16_dual(
    const unsigned short* __restrict__ Mer, const unsigned short* __restrict__ Mpr,
    const int* __restrict__ deg,
    const float* __restrict__ st_er, const float* __restrict__ st_pr,
    const float* __restrict__ g_er, const float* __restrict__ bt_er,
    const float* __restrict__ g_pr, const float* __restrict__ bt_pr,
    const float* __restrict__ Wer, const float* __restrict__ Wpr,
    float* __restrict__ zP, float* __restrict__ stp_er, float* __restrict__ stp_pr,
    int Nn, float invE) {
  __shared__ float sce_l[128], she_l[128], scp_l[128], shp_l[128];
  __shared__ float red[4][4];
  int tid = threadIdx.x;
  if (tid < 128) {
    float sme = 0.f, sqe = 0.f, smp = 0.f, sqp = 0.f;
#pragma unroll
    for (int k = 0; k < 16; ++k) {
      sme += st_er[k * 256 + 2 * tid];
      sqe += st_er[k * 256 + 2 * tid + 1];
      smp += st_pr[k * 256 + 2 * tid];
      sqp += st_pr[k * 256 + 2 * tid + 1];
    }
    float mean = sme * invE;
    float var = sqe * invE - mean * mean;
    float sc = g_er[tid] * rsqrtf(var + EPS);
    she_l[tid] = bt_er[tid] - mean * sc;
    sce_l[tid] = (g_er[tid] < 0.f) ? -sc : sc;
    mean = smp * invE;
    var = sqp * invE - mean * mean;
    sc = g_pr[tid] * rsqrtf(var + EPS);
    shp_l[tid] = bt_pr[tid] - mean * sc;
    scp_l[tid] = (g_pr[tid] < 0.f) ? -sc : sc;
  }
  __syncthreads();
  int sub = tid & 15, c0 = sub * 8;
  float sce[8], she[8], scp[8], shp[8], we[8], wp[8];
#pragma unroll
  for (int j = 0; j < 8; ++j) {
    sce[j] = sce_l[c0 + j]; she[j] = she_l[c0 + j];
    scp[j] = scp_l[c0 + j]; shp[j] = shp_l[c0 + j];
    we[j] = Wer[c0 + j]; wp[j] = Wpr[c0 + j];
  }
  int g0 = (blockIdx.x * 256 + tid) >> 4;
  int gstride = gridDim.x * 16;
  bool leader = (sub == 0);
  float s0 = 0.f, ss0 = 0.f, s1 = 0.f, ss1 = 0.f;
  for (int n = g0; n < Nn; n += gstride) {
    float d0 = 0.f, d1 = 0.f;
    if (deg[n] > 0) {
      uint4 ve = ((const uint4*)(Mer + (size_t)n * 128))[sub];
      uint4 vp = ((const uint4*)(Mpr + (size_t)n * 128))[sub];
      unsigned wea[4] = {ve.x, ve.y, ve.z, ve.w};
      unsigned wpa[4] = {vp.x, vp.y, vp.z, vp.w};
#pragma unroll
      for (int u = 0; u < 4; ++u) {
        float te0 = blo(wea[u]) * sce[2 * u] + she[2 * u];
        float te1 = bhi(wea[u]) * sce[2 * u + 1] + she[2 * u + 1];
        float tp0 = blo(wpa[u]) * scp[2 * u] + shp[2 * u];
        float tp1 = bhi(wpa[u]) * scp[2 * u + 1] + shp[2 * u + 1];
        d0 += elu_f(te0) * we[2 * u] + elu_f(te1) * we[2 * u + 1];
        d1 += elu_f(tp0) * wp[2 * u] + elu_f(tp1) * wp[2 * u + 1];
      }
    }
#pragma unroll
    for (int off = 1; off < 16; off <<= 1) {
      d0 += __shfl_xor(d0, off);
      d1 += __shfl_xor(d1, off);
    }
    if (leader) {
      zP[n * 2] = d0;
      zP[n * 2 + 1] = d1;
      s0 += d0; ss0 += d0 * d0; s1 += d1; ss1 += d1 * d1;
    }
  }
  s0 += __shfl_xor(s0, 16);  s0 += __shfl_xor(s0, 32);
  s1 += __shfl_xor(s1, 16);  s1 += __shfl_xor(s1, 32);
  ss0 += __shfl_xor(ss0, 16); ss0 += __shfl_xor(ss0, 32);
  ss1 += __shfl_xor(ss1, 16); ss1 += __shfl_xor(ss1, 32);
  int wv = tid >> 6;
  if ((tid & 63) == 0) { red[wv][0] = s0; red[wv][1] = s1; red[wv][2] = ss0; red[wv][3] = ss1; }
  __syncthreads();
  if (tid < 4) {
    float v = red[0][tid] + red[1][tid] + red[2][tid] + red[3][tid];
    if (tid == 0) atomicAdd(&stp_er[0], v);
    else if (tid == 1) atomicAdd(&stp_pr[0], v);
    else if (tid == 2) atomicAdd(&stp_er[128], v);
    else atomicAdd(&stp_pr[128], v);
  }
}

// dual terminal: col0 <- er, col1 <- pr
__global__ __launch_bounds__(256) void post_phase2_dual(const float* __restrict__ zP,
    const int* __restrict__ batch, const float* __restrict__ counts,
    const float* __restrict__ st_er, const float* __restrict__ st_pr,
    const float* __restrict__ g_er, const float* __restrict__ bt_er,
    const float* __restrict__ g_pr, const float* __restrict__ bt_pr,
    float* __restrict__ out, int Nrows, float invN) {
  __shared__ float lacc[128];
  if (threadIdx.x < 128) lacc[threadIdx.x] = 0.f;
  __syncthreads();
  float m0 = st_er[0] * invN;
  float v0 = st_er[128] * invN - m0 * m0;
  float scale0 = g_er[0] * rsqrtf(v0 + EPS);
  float shift0 = bt_er[0] - m0 * scale0;
  float m1 = st_pr[0] * invN;
  float v1 = st_pr[128] * invN - m1 * m1;
  float scale1 = g_pr[0] * rsqrtf(v1 + EPS);
  float shift1 = bt_pr[0] - m1 * scale1;
  int i0 = blockIdx.x * 256 + threadIdx.x;
  int stride = gridDim.x * 256;
  for (int n = i0; n < Nrows; n += stride) {
    int gi = batch[n];
    float y0 = elu_f(zP[n * 2] * scale0 + shift0);
    float y1 = elu_f(zP[n * 2 + 1] * scale1 + shift1);
    atomicAdd(&lacc[gi * 2], y0);
    atomicAdd(&lacc[gi * 2 + 1], y1);
  }
  __syncthreads();
  if (threadIdx.x < 128) {
    int gi = threadIdx.x >> 1, p = threadIdx.x & 1;
    float v = lacc[threadIdx.x];
    if (v != 0.f)
      atomicAdd(&out[gi * 2 + p], v / fmaxf(counts[gi * 16], 1.f));
  }
}

extern "C" void kernel_launch(void* const* d_in, const int* in_sizes, int n_in,
                              void* d_out, int out_size, void* d_ws, size_t ws_size,
                              hipStream_t stream) {
  const float* x       = (const float*)d_in[0];
  const int*   ei      = (const int*)d_in[1];
  const int*   batch   = (const int*)d_in[2];
  const float* init_W  = (const float*)d_in[3];
  const float* init_g  = (const float*)d_in[5];
  const float* init_bt = (const float*)d_in[6];
  const float* mid_W   = (const float*)d_in[7];
  const float* mid_g   = (const float*)d_in[9];
  const float* mid_bt  = (const float*)d_in[10];
  const float* er_W    = (const float*)d_in[11];
  const float* er_g    = (const float*)d_in[13];
  const float* er_bt   = (const float*)d_in[14];
  const float* pr_W    = (const float*)d_in[15];
  const float* pr_g    = (const float*)d_in[17];
  const float* pr_bt   = (const float*)d_in[18];
  const float* spost_W  = (const float*)d_in[19];
  const float* spost_g  = (const float*)d_in[21];
  const float* spost_bt = (const float*)d_in[22];
  const float* erpost_W  = (const float*)d_in[23];
  const float* erpost_g  = (const float*)d_in[25];
  const float* erpost_bt = (const float*)d_in[26];
  const float* prpost_W  = (const float*)d_in[27];
  const float* prpost_g  = (const float*)d_in[29];
  const float* prpost_bt = (const float*)d_in[30];

  int N = in_sizes[0] / 128;
  int E = in_sizes[1] / 2;
  float invN = 1.f / (float)N;
  float invE = 1.f / (float)E;
  float* out = (float*)d_out;

  const int CONV_BLKS = 2048;
  int nbuck = (N + 255) >> 8;
  int p1b = (E + P1_CHUNK - 1) / P1_CHUNK;

  size_t NB = (size_t)N * 128;
  unsigned short* TbI = (unsigned short*)d_ws;
  unsigned short* Tb0 = TbI + NB;
  unsigned short* Tb1 = Tb0 + NB;
  unsigned short* Tb2 = Tb1 + NB;
  unsigned short* Tb3 = Tb2 + NB;
  unsigned short* MxB = Tb3 + NB;
  unsigned short* MxB2 = MxB + NB;
  float* zP     = (float*)(MxB2 + NB);
  float* counts = zP + (size_t)2 * N;
  float* stats  = counts + 1024;               // 5 slots x (16 copies x 256) node stats
  float* post   = stats + 5 * 4096;            // 5 slots x 512 post stats
  unsigned short* WT = (unsigned short*)(post + 5 * 512);  // 9 x 16384
  int* deg        = (int*)(WT + 9 * 16384);
  int* rowstart   = deg + N;
  int* bucketbase = rowstart + N;              // 257 (pad 320)
  int* gcursor    = bucketbase + 320;          // 256 x 16 (padded)
  int* partials   = gcursor + 256 * 16;        // 64 x 256
  unsigned* binned = (unsigned*)(partials + 64 * 256);   // E
  unsigned short* csr_src = (unsigned short*)(binned + E); // E (ushort)

  int gemmGrid = (N + 63) / 64;

  hipMemsetAsync(d_out, 0, out_size * sizeof(float), stream);
  hipMemsetAsync(counts, 0, (1024 + 5 * 4096 + 5 * 512) * sizeof(float), stream);

  // weight prep + CSR p0 count/hist merged
  const int* e_src = ei;
  const int* e_dst = ei + E;
  prep_csr0<<<448, 256, 0, stream>>>(init_W, mid_W, er_W, pr_W, mid_g, er_g, pr_g, WT,
                                     e_dst, partials, E, batch, counts, N);
  csr_p0_scan<<<1, 256, 0, stream>>>(partials, 64, bucketbase, gcursor);

  // ---- merged: CSR p1 bin + init GEMM (fp32 x -> TbI, node stats fused) ----
  p1_initgemm<<<p1b + gemmGrid, 256, 0, stream>>>(e_src, e_dst, gcursor, binned, E, p1b,
      (const void*)x, WT, TbI, stats, N);

  // ---- merged: CSR p2 sort + mid0 ACT-GEMM (gelu(BN(TbI)) -> Tb0,Tb1; init zP/stp fused) ----
  p2_act0<<<nbuck + gemmGrid, 256, 0, stream>>>(binned, bucketbase, csr_src, deg, rowstart,
      N, nbuck, TbI, WT + 1 * 16384, WT + 2 * 16384, Tb0, Tb1,
      stats, init_g, init_bt, spost_W, zP, post + 0 * 512, invN);

  // ---- conv0 -> MxB + stats1; tail finishes init-layer phase2 ----
  conv_pass<<<CONV_BLKS + 32, 256, 0, stream>>>(Tb0, Tb1, csr_src, rowstart, deg, mid_g,
      MxB, stats + 1 * 4096, N, CONV_BLKS,
      zP, batch, counts, post + 0 * 512, spost_g, spost_bt, out, invN);

  // ---- mid1 ACT-GEMM: elu(BN(MxB)) -> Tb0,Tb1 ; mid0 zP + post stats fused ----
  gemm_act<2, 2><<<gemmGrid, 256, 0, stream>>>(MxB,
      WT + 3 * 16384, WT + 4 * 16384, nullptr, nullptr, Tb0, Tb1, nullptr, nullptr,
      stats + 1 * 4096, mid_g, mid_bt, deg, spost_W + 256, zP, post + 1 * 512, invE, N);

  // ---- conv1 -> MxB + stats2; tail finishes mid0 phase2 ----
  conv_pass<<<CONV_BLKS + 32, 256, 0, stream>>>(Tb0, Tb1, csr_src, rowstart, deg, mid_g + 128,
      MxB, stats + 2 * 4096, N, CONV_BLKS,
      zP, batch, counts, post + 1 * 512, spost_g + 2, spost_bt + 2, out, invN);

  // ---- er/pr ACT-GEMM: elu(BN(MxB)) -> Tb0..Tb3 ; mid1 zP + post stats fused ----
  gemm_act<4, 2><<<gemmGrid, 256, 0, stream>>>(MxB,
      WT + 5 * 16384, WT + 6 * 16384, WT + 7 * 16384, WT + 8 * 16384,
      Tb0, Tb1, Tb2, Tb3,
      stats + 2 * 4096, mid_g + 128, mid_bt + 128, deg, spost_W + 512,
      zP, post + 2 * 512, invE, N);

  // ---- dual conv -> MxB, MxB2 + stats3/4; tail finishes mid1 phase2 ----
  conv_pass_dual<<<CONV_BLKS + 32, 256, 0, stream>>>(Tb0, Tb1, Tb2, Tb3, csr_src, rowstart, deg,
      er_g, pr_g, MxB, MxB2, stats + 3 * 4096, stats + 4 * 4096, N, CONV_BLKS,
      zP, batch, counts, post + 2 * 512, spost_g + 4, spost_bt + 4, out, invN);

  // ---- terminal er/pr posts ----
  fused_post16_dual<<<512, 256, 0, stream>>>(MxB, MxB2, deg,
      stats + 3 * 4096, stats + 4 * 4096, er_g, er_bt, pr_g, pr_bt,
      erpost_W, prpost_W, zP, post + 3 * 512, post + 4 * 512, N, invE);
  post_phase2_dual<<<32, 256, 0, stream>>>(zP, batch, counts,
      post + 3 * 512, post + 4 * 512, erpost_g, erpost_bt, prpost_g, prpost_bt,
      out, N, invN);
}

// Round 9
// 365.442 us; speedup vs baseline: 1.1027x; 1.1027x over previous
//
#include <hip/hip_runtime.h>
#include <math.h>

#define EPS 1e-5f

typedef float f32x4v __attribute__((ext_vector_type(4)));
typedef short s16x8  __attribute__((ext_vector_type(8)));

__device__ __forceinline__ float elu_f(float x) { return x > 0.f ? x : expm1f(x); }
__device__ __forceinline__ float blo(unsigned u) { return __uint_as_float(u << 16); }
__device__ __forceinline__ float bhi(unsigned u) { return __uint_as_float(u & 0xffff0000u); }
__device__ __forceinline__ unsigned f2b(float f) {  // RNE float->bf16
  unsigned u = __float_as_uint(f);
  unsigned r = ((u >> 16) & 1u) + 0x7fffu;
  return (u + r) >> 16;
}
__device__ __forceinline__ unsigned pack2(float a, float b) {
  return f2b(a) | (f2b(b) << 16);
}

// ---------------- merged: weight prep (blocks 0-319) + CSR p0 count/hist (blocks 320-447) ----------------
__global__ __launch_bounds__(256) void prep_csr0(const float* __restrict__ init_W,
    const float* __restrict__ mid_W, const float* __restrict__ er_W,
    const float* __restrict__ pr_W, const float* __restrict__ mid_g,
    const float* __restrict__ er_g, const float* __restrict__ pr_g,
    unsigned short* __restrict__ WT,
    const int* __restrict__ dst, int* __restrict__ partials, int Ecnt,
    const int* __restrict__ batch, float* __restrict__ counts, int Nn) {
  if (blockIdx.x < 320) {
    int grp = blockIdx.x >> 6;
    int i = (blockIdx.x & 63) * 256 + threadIdx.x;
    if (i >= 16384) return;
    int k = i >> 7, c = i & 127;
    if (grp == 0) {
      WT[c * 128 + k] = (unsigned short)f2b(init_W[k * 128 + c]);
      return;
    }
    const float* W; const float* g; unsigned short* Wd; unsigned short* W2;
    if (grp == 1)      { W = mid_W;             g = mid_g;       Wd = WT + 1 * 16384; W2 = WT + 2 * 16384; }
    else if (grp == 2) { W = mid_W + 256 * 128; g = mid_g + 128; Wd = WT + 3 * 16384; W2 = WT + 4 * 16384; }
    else if (grp == 3) { W = er_W;              g = er_g;        Wd = WT + 5 * 16384; W2 = WT + 6 * 16384; }
    else               { W = pr_W;              g = pr_g;        Wd = WT + 7 * 16384; W2 = WT + 8 * 16384; }
    float sg = (g[c] >= 0.f) ? 1.f : -1.f;
    float w1 = W[k * 128 + c];
    float w2 = W[(k + 128) * 128 + c];
    Wd[c * 128 + k] = (unsigned short)f2b((w1 - w2) * sg);
    W2[c * 128 + k] = (unsigned short)f2b(w2 * sg);
  } else {
    int b = blockIdx.x - 320;
    if (b < 64) {
      __shared__ int cnt[256];
      cnt[threadIdx.x] = 0;
      __syncthreads();
      int i0 = b * 256 + threadIdx.x, stride = 64 * 256;
      for (int e = i0; e < Ecnt; e += stride) atomicAdd(&cnt[(unsigned)dst[e] >> 8], 1);
      __syncthreads();
      partials[b * 256 + threadIdx.x] = cnt[threadIdx.x];
    } else {
      __shared__ float lc[64];
      if (threadIdx.x < 64) lc[threadIdx.x] = 0.f;
      __syncthreads();
      int i0 = (b - 64) * 256 + threadIdx.x, stride = 64 * 256;
      for (int n = i0; n < Nn; n += stride) atomicAdd(&lc[batch[n]], 1.f);
      __syncthreads();
      if (threadIdx.x < 64 && lc[threadIdx.x] != 0.f)
        atomicAdd(&counts[threadIdx.x * 16], lc[threadIdx.x]);
    }
  }
}

__global__ __launch_bounds__(256) void csr_p0_scan(const int* __restrict__ partials,
    int nblk, int* __restrict__ bucket_base, int* __restrict__ gcursor) {
  __shared__ int sc[256];
  int b = threadIdx.x;
  int s = 0;
  for (int k = 0; k < nblk; ++k) s += partials[k * 256 + b];
  sc[b] = s;
  __syncthreads();
  for (int off = 1; off < 256; off <<= 1) {
    int t = (b >= off) ? sc[b - off] : 0;
    __syncthreads();
    sc[b] += t;
    __syncthreads();
  }
  int excl = sc[b] - s;
  bucket_base[b] = excl;
  gcursor[b * 16] = excl;
  if (b == 255) bucket_base[256] = sc[255];
}

#define P1_CHUNK 4096
__device__ __forceinline__ void csr_p1_body(int bid, const int* __restrict__ src,
    const int* __restrict__ dst, int* __restrict__ gcursor,
    unsigned* __restrict__ binned, int Ecnt) {
  __shared__ unsigned stage[P1_CHUNK];
  __shared__ int cnt[256], lbase[256], gbase[256], lcur[256], sc[256];
  int tid = threadIdx.x;
  int e0 = bid * P1_CHUNK;
  int ecnt = Ecnt - e0; if (ecnt > P1_CHUNK) ecnt = P1_CHUNK;
  cnt[tid] = 0;
  __syncthreads();
  for (int i = tid; i < ecnt; i += 256) atomicAdd(&cnt[(unsigned)dst[e0 + i] >> 8], 1);
  __syncthreads();
  sc[tid] = cnt[tid];
  __syncthreads();
  for (int off = 1; off < 256; off <<= 1) {
    int t = (tid >= off) ? sc[tid - off] : 0;
    __syncthreads();
    sc[tid] += t;
    __syncthreads();
  }
  lbase[tid] = sc[tid] - cnt[tid];
  lcur[tid] = lbase[tid];
  gbase[tid] = (cnt[tid] > 0) ? atomicAdd(&gcursor[tid * 16], cnt[tid]) : 0;
  __syncthreads();
  for (int i = tid; i < ecnt; i += 256) {
    int d = dst[e0 + i], s = src[e0 + i];
    int bk = (unsigned)d >> 8;
    int p = atomicAdd(&lcur[bk], 1);
    stage[p] = ((unsigned)bk << 24) | ((unsigned)(d & 255) << 16) | (unsigned)s;
  }
  __syncthreads();
  for (int i = tid; i < ecnt; i += 256) {
    unsigned v = stage[i];
    int bk = v >> 24;
    binned[gbase[bk] + (i - lbase[bk])] = v;
  }
}

#define P2_CAP 12288
__device__ __forceinline__ void csr_p2_body(int bid, const unsigned* __restrict__ binned,
    const int* __restrict__ bucket_base, unsigned short* __restrict__ csr_src,
    int* __restrict__ deg, int* __restrict__ rowstart, int Nn) {
  __shared__ unsigned short stage[P2_CAP];
  __shared__ int cnt[256], lbase[256], lcur[256], sc[256];
  int b = bid, tid = threadIdx.x;
  int base = bucket_base[b];
  int bcnt = bucket_base[b + 1] - base;
  if (bcnt > P2_CAP) bcnt = P2_CAP;
  cnt[tid] = 0;
  __syncthreads();
  for (int i = tid; i < bcnt; i += 256) atomicAdd(&cnt[(binned[base + i] >> 16) & 255], 1);
  __syncthreads();
  sc[tid] = cnt[tid];
  __syncthreads();
  for (int off = 1; off < 256; off <<= 1) {
    int t = (tid >= off) ? sc[tid - off] : 0;
    __syncthreads();
    sc[tid] += t;
    __syncthreads();
  }
  lbase[tid] = sc[tid] - cnt[tid];
  lcur[tid] = lbase[tid];
  int node = b * 256 + tid;
  if (node < Nn) { deg[node] = cnt[tid]; rowstart[node] = base + lbase[tid]; }
  __syncthreads();
  for (int i = tid; i < bcnt; i += 256) {
    unsigned v = binned[base + i];
    int j = (v >> 16) & 255;
    int p = atomicAdd(&lcur[j], 1);
    stage[p] = (unsigned short)(v & 0xffffu);
  }
  __syncthreads();
  for (int i = tid; i < bcnt; i += 256) csr_src[base + i] = stage[i];
}

// ---------------- plain MFMA GEMM body (init layer: fp32 in, fused node stats) ----------------
template<int XF32, int NMAT, int STATS>
__device__ __forceinline__ void gemm_mfma_body(int bid, const void* __restrict__ Xv,
    const unsigned short* __restrict__ W0t, const unsigned short* __restrict__ W1t,
    const unsigned short* __restrict__ W2t, const unsigned short* __restrict__ W3t,
    unsigned short* __restrict__ Y0, unsigned short* __restrict__ Y1,
    unsigned short* __restrict__ Y2, unsigned short* __restrict__ Y3,
    float* __restrict__ stOut, int Nrows) {
  int tid = threadIdx.x, lane = tid & 63, wv = tid >> 6;
  int r0 = bid * 64;
  int rlo = lane & 15, kg = lane >> 4;
  s16x8 zf = {0, 0, 0, 0, 0, 0, 0, 0};
  s16x8 af[4][4];
#pragma unroll
  for (int rg = 0; rg < 4; ++rg) {
    int arow = r0 + rg * 16 + rlo;
    if (arow < Nrows) {
      if (XF32) {
        const float* xr = (const float*)Xv + (size_t)arow * 128 + kg * 8;
#pragma unroll
        for (int s2 = 0; s2 < 4; ++s2) {
          float4 a = *(const float4*)(xr + s2 * 32);
          float4 b = *(const float4*)(xr + s2 * 32 + 4);
          s16x8 t;
          t[0] = (short)f2b(a.x); t[1] = (short)f2b(a.y);
          t[2] = (short)f2b(a.z); t[3] = (short)f2b(a.w);
          t[4] = (short)f2b(b.x); t[5] = (short)f2b(b.y);
          t[6] = (short)f2b(b.z); t[7] = (short)f2b(b.w);
          af[rg][s2] = t;
        }
      } else {
        const unsigned short* xr = (const unsigned short*)Xv + (size_t)arow * 128 + kg * 8;
#pragma unroll
        for (int s2 = 0; s2 < 4; ++s2) af[rg][s2] = *(const s16x8*)(xr + s2 * 32);
      }
    } else {
#pragma unroll
      for (int s2 = 0; s2 < 4; ++s2) af[rg][s2] = zf;
    }
  }
  const unsigned short* Ws[4] = {W0t, W1t, W2t, W3t};
  unsigned short* Ys[4] = {Y0, Y1, Y2, Y3};
#pragma unroll
  for (int o = 0; o < NMAT; ++o) {
    const unsigned short* Wt = Ws[o];
    unsigned short* Y = Ys[o];
#pragma unroll
    for (int t = 0; t < 2; ++t) {
      int nt = wv * 2 + t;
      const unsigned short* wp = Wt + (size_t)(nt * 16 + rlo) * 128 + kg * 8;
      s16x8 wf[4];
#pragma unroll
      for (int s2 = 0; s2 < 4; ++s2) wf[s2] = *(const s16x8*)(wp + s2 * 32);
      f32x4v acc[4];
#pragma unroll
      for (int rg = 0; rg < 4; ++rg) acc[rg] = (f32x4v){0.f, 0.f, 0.f, 0.f};
#pragma unroll
      for (int s2 = 0; s2 < 4; ++s2)
#pragma unroll
        for (int rg = 0; rg < 4; ++rg)
          acc[rg] = __builtin_amdgcn_mfma_f32_16x16x32_bf16(wf[s2], af[rg][s2], acc[rg], 0, 0, 0);
      float ps0 = 0.f, ps1 = 0.f, ps2 = 0.f, ps3 = 0.f;
      float pq0 = 0.f, pq1 = 0.f, pq2 = 0.f, pq3 = 0.f;
#pragma unroll
      for (int rg = 0; rg < 4; ++rg) {
        int arow = r0 + rg * 16 + rlo;
        if (arow < Nrows) {
          uint2 ov;
          ov.x = pack2(acc[rg][0], acc[rg][1]);
          ov.y = pack2(acc[rg][2], acc[rg][3]);
          *(uint2*)(Y + (size_t)arow * 128 + nt * 16 + kg * 4) = ov;
          if (STATS) {
            float y0 = blo(ov.x), y1 = bhi(ov.x), y2 = blo(ov.y), y3 = bhi(ov.y);
            ps0 += y0; pq0 += y0 * y0;
            ps1 += y1; pq1 += y1 * y1;
            ps2 += y2; pq2 += y2 * y2;
            ps3 += y3; pq3 += y3 * y3;
          }
        }
      }
      if (STATS) {
#pragma unroll
        for (int off = 1; off < 16; off <<= 1) {
          ps0 += __shfl_xor(ps0, off); pq0 += __shfl_xor(pq0, off);
          ps1 += __shfl_xor(ps1, off); pq1 += __shfl_xor(pq1, off);
          ps2 += __shfl_xor(ps2, off); pq2 += __shfl_xor(pq2, off);
          ps3 += __shfl_xor(ps3, off); pq3 += __shfl_xor(pq3, off);
        }
        if (rlo == 0) {
          int col = nt * 16 + kg * 4;
          float* sb = stOut + (size_t)(bid & 15) * 256;
          atomicAdd(&sb[2 * col + 0], ps0); atomicAdd(&sb[2 * col + 1], pq0);
          atomicAdd(&sb[2 * (col + 1)], ps1); atomicAdd(&sb[2 * (col + 1) + 1], pq1);
          atomicAdd(&sb[2 * (col + 2)], ps2); atomicAdd(&sb[2 * (col + 2) + 1], pq2);
          atomicAdd(&sb[2 * (col + 3)], ps3); atomicAdd(&sb[2 * (col + 3) + 1], pq3);
        }
      }
    }
  }
}

// ---------------- activation-fused GEMM body: phase A (BN+act -> LDS, zP dot) ; phase B (MFMA) ----
template<int NMAT, int ACT>
__device__ __forceinline__ void gemm_act_body(int bid, const unsigned short* __restrict__ Xv,
    const unsigned short* __restrict__ W0t, const unsigned short* __restrict__ W1t,
    const unsigned short* __restrict__ W2t, const unsigned short* __restrict__ W3t,
    unsigned short* __restrict__ Y0, unsigned short* __restrict__ Y1,
    unsigned short* __restrict__ Y2, unsigned short* __restrict__ Y3,
    const float* __restrict__ stn, const float* __restrict__ g,
    const float* __restrict__ bt, const int* __restrict__ deg,
    const float* __restrict__ Wp, float* __restrict__ zP, float* __restrict__ stp,
    float invCnt, int Nrows) {
  __shared__ unsigned short hl[64][136];
  __shared__ float lsc[128], lsh[128], lw0[128], lw1[128];
  __shared__ float red[4][4];
  int tid = threadIdx.x, lane = tid & 63, wv = tid >> 6;
  int r0 = bid * 64;
  int rlo = lane & 15, kg = lane >> 4;
  if (tid < 128) {
    float sm = 0.f, sq = 0.f;
#pragma unroll
    for (int k = 0; k < 16; ++k) {
      sm += stn[k * 256 + 2 * tid];
      sq += stn[k * 256 + 2 * tid + 1];
    }
    float mean = sm * invCnt;
    float var = sq * invCnt - mean * mean;
    float sc = g[tid] * rsqrtf(var + EPS);
    float sh = bt[tid] - mean * sc;
    if (ACT == 2 && g[tid] < 0.f) sc = -sc;
    lsc[tid] = sc; lsh[tid] = sh;
    lw0[tid] = Wp[tid * 2]; lw1[tid] = Wp[tid * 2 + 1];
  }
  __syncthreads();
  {
    int row = tid >> 2, q = tid & 3;
    int arow = r0 + row;
    bool rok = arow < Nrows;
    int lrow = rok ? arow : 0;
    float live = 1.f;
    if (ACT == 2) live = (rok && deg[arow] > 0) ? 1.f : 0.f;
    else live = rok ? 1.f : 0.f;
    const uint4* xr = (const uint4*)(Xv + (size_t)lrow * 128 + q * 32);
    float dd0 = 0.f, dd1 = 0.f;
#pragma unroll
    for (int b = 0; b < 4; ++b) {
      uint4 v = xr[b];
      unsigned w[4] = {v.x, v.y, v.z, v.w};
      int cb = q * 32 + b * 8;
#pragma unroll
      for (int u = 0; u < 4; ++u) {
        int c = cb + 2 * u;
        float t0 = blo(w[u]) * lsc[c] + lsh[c];
        float t1 = bhi(w[u]) * lsc[c + 1] + lsh[c + 1];
        float y0, y1;
        if (ACT == 1) {
          y0 = 0.5f * t0 * (1.f + erff(t0 * 0.70710678118f));
          y1 = 0.5f * t1 * (1.f + erff(t1 * 0.70710678118f));
        } else {
          y0 = elu_f(t0); y1 = elu_f(t1);
        }
        y0 *= live; y1 *= live;
        *(unsigned*)&hl[row][c] = pack2(y0, y1);
        dd0 += y0 * lw0[c] + y1 * lw0[c + 1];
        dd1 += y0 * lw1[c] + y1 * lw1[c + 1];
      }
    }
    dd0 += __shfl_xor(dd0, 1); dd0 += __shfl_xor(dd0, 2);
    dd1 += __shfl_xor(dd1, 1); dd1 += __shfl_xor(dd1, 2);
    if (q == 0 && rok) {
      zP[(size_t)arow * 2] = dd0;
      zP[(size_t)arow * 2 + 1] = dd1;
    }
    float s0v = (q == 0 && rok) ? dd0 : 0.f;
    float s1v = (q == 0 && rok) ? dd1 : 0.f;
    float q0v = s0v * s0v, q1v = s1v * s1v;
#pragma unroll
    for (int off = 4; off < 64; off <<= 1) {
      s0v += __shfl_xor(s0v, off); s1v += __shfl_xor(s1v, off);
      q0v += __shfl_xor(q0v, off); q1v += __shfl_xor(q1v, off);
    }
    if (lane == 0) { red[wv][0] = s0v; red[wv][1] = s1v; red[wv][2] = q0v; red[wv][3] = q1v; }
  }
  __syncthreads();
  if (tid < 4) {
    float v = red[0][tid] + red[1][tid] + red[2][tid] + red[3][tid];
    atomicAdd(&stp[tid * 64], v);
  }
  s16x8 af[4][4];
#pragma unroll
  for (int rg = 0; rg < 4; ++rg)
#pragma unroll
    for (int s2 = 0; s2 < 4; ++s2)
      af[rg][s2] = *(const s16x8*)&hl[rg * 16 + rlo][kg * 8 + s2 * 32];
  const unsigned short* Ws[4] = {W0t, W1t, W2t, W3t};
  unsigned short* Ys[4] = {Y0, Y1, Y2, Y3};
#pragma unroll
  for (int o = 0; o < NMAT; ++o) {
    const unsigned short* Wt = Ws[o];
    unsigned short* Y = Ys[o];
#pragma unroll
    for (int t = 0; t < 2; ++t) {
      int nt = wv * 2 + t;
      const unsigned short* wp = Wt + (size_t)(nt * 16 + rlo) * 128 + kg * 8;
      s16x8 wf[4];
#pragma unroll
      for (int s2 = 0; s2 < 4; ++s2) wf[s2] = *(const s16x8*)(wp + s2 * 32);
      f32x4v acc[4];
#pragma unroll
      for (int rg = 0; rg < 4; ++rg) acc[rg] = (f32x4v){0.f, 0.f, 0.f, 0.f};
#pragma unroll
      for (int s2 = 0; s2 < 4; ++s2)
#pragma unroll
        for (int rg = 0; rg < 4; ++rg)
          acc[rg] = __builtin_amdgcn_mfma_f32_16x16x32_bf16(wf[s2], af[rg][s2], acc[rg], 0, 0, 0);
#pragma unroll
      for (int rg = 0; rg < 4; ++rg) {
        int arow = r0 + rg * 16 + rlo;
        if (arow < Nrows) {
          uint2 ov;
          ov.x = pack2(acc[rg][0], acc[rg][1]);
          ov.y = pack2(acc[rg][2], acc[rg][3]);
          *(uint2*)(Y + (size_t)arow * 128 + nt * 16 + kg * 4) = ov;
        }
      }
    }
  }
}

// standalone ACT-GEMM kernels (mid1, er/pr)
template<int NMAT, int ACT>
__global__ __launch_bounds__(256, 3) void gemm_act(const unsigned short* __restrict__ Xv,
    const unsigned short* __restrict__ W0t, const unsigned short* __restrict__ W1t,
    const unsigned short* __restrict__ W2t, const unsigned short* __restrict__ W3t,
    unsigned short* __restrict__ Y0, unsigned short* __restrict__ Y1,
    unsigned short* __restrict__ Y2, unsigned short* __restrict__ Y3,
    const float* __restrict__ stn, const float* __restrict__ g,
    const float* __restrict__ bt, const int* __restrict__ deg,
    const float* __restrict__ Wp, float* __restrict__ zP, float* __restrict__ stp,
    float invCnt, int Nrows) {
  gemm_act_body<NMAT, ACT>(blockIdx.x, Xv, W0t, W1t, W2t, W3t, Y0, Y1, Y2, Y3,
                           stn, g, bt, deg, Wp, zP, stp, invCnt, Nrows);
}

// merged: CSR p1 bin (blocks 0..p1b-1) + init GEMM (blocks p1b..)
__global__ __launch_bounds__(256, 3) void p1_initgemm(
    const int* __restrict__ src, const int* __restrict__ dst, int* __restrict__ gcursor,
    unsigned* __restrict__ binned, int Ecnt, int p1b,
    const void* __restrict__ Xv, const unsigned short* __restrict__ W0t,
    unsigned short* __restrict__ Y0, float* __restrict__ stOut, int Nrows) {
  if ((int)blockIdx.x < p1b) {
    csr_p1_body(blockIdx.x, src, dst, gcursor, binned, Ecnt);
  } else {
    gemm_mfma_body<1, 1, 1>(blockIdx.x - p1b, Xv, W0t, nullptr, nullptr, nullptr,
                            Y0, nullptr, nullptr, nullptr, stOut, Nrows);
  }
}

// merged: CSR p2 sort (blocks 0..nbuck-1) + mid0 ACT-GEMM (blocks nbuck..)
// Safe: ACT=1 path never reads deg (written here by p2).
__global__ __launch_bounds__(256, 3) void p2_act0(
    const unsigned* __restrict__ binned, const int* __restrict__ bucket_base,
    unsigned short* __restrict__ csr_src, int* __restrict__ deg,
    int* __restrict__ rowstart, int Nn, int nbuck,
    const unsigned short* __restrict__ Xv,
    const unsigned short* __restrict__ W0t, const unsigned short* __restrict__ W1t,
    unsigned short* __restrict__ Y0, unsigned short* __restrict__ Y1,
    const float* __restrict__ stn, const float* __restrict__ g,
    const float* __restrict__ bt, const float* __restrict__ Wp,
    float* __restrict__ zP, float* __restrict__ stp, float invCnt) {
  if ((int)blockIdx.x < nbuck) {
    csr_p2_body(blockIdx.x, binned, bucket_base, csr_src, deg, rowstart, Nn);
  } else {
    gemm_act_body<2, 1>(blockIdx.x - nbuck, Xv, W0t, W1t, nullptr, nullptr,
                        Y0, Y1, nullptr, nullptr, stn, g, bt, nullptr,
                        Wp, zP, stp, invCnt, Nn);
  }
}

// ---------------- conv pass (R4-proven body: combined-value accumulation) + phase2 tail ----------
// stpp format: [0]=sum0, [64]=sum1, [128]=ssq0, [192]=ssq1
__global__ __launch_bounds__(256, 8) void conv_pass(const unsigned short* __restrict__ A,
    const unsigned short* __restrict__ B, const unsigned short* __restrict__ csr_src,
    const int* __restrict__ rowstart, const int* __restrict__ deg,
    const float* __restrict__ g, unsigned short* __restrict__ Mx,
    float* __restrict__ st, int Nn, int convBlks,
    const float* __restrict__ zPp, const int* __restrict__ batch,
    const float* __restrict__ counts, const float* __restrict__ stpp,
    const float* __restrict__ g2, const float* __restrict__ bt2,
    float* __restrict__ out, float invN) {
  __shared__ float s_sum[128], s_ssq[128];
  int tid = threadIdx.x;
  if ((int)blockIdx.x >= convBlks) {
    __shared__ float lacc[128];
    if (tid < 128) lacc[tid] = 0.f;
    __syncthreads();
    float m0 = stpp[0] * invN, v0 = stpp[128] * invN - m0 * m0;
    float scale0 = g2[0] * rsqrtf(v0 + EPS), shift0 = bt2[0] - m0 * scale0;
    float m1 = stpp[64] * invN, v1 = stpp[192] * invN - m1 * m1;
    float scale1 = g2[1] * rsqrtf(v1 + EPS), shift1 = bt2[1] - m1 * scale1;
    int i0 = (blockIdx.x - convBlks) * 256 + tid;
    int stride = 32 * 256;
    for (int n = i0; n < Nn; n += stride) {
      int gi = batch[n];
      atomicAdd(&lacc[gi * 2], elu_f(zPp[n * 2] * scale0 + shift0));
      atomicAdd(&lacc[gi * 2 + 1], elu_f(zPp[n * 2 + 1] * scale1 + shift1));
    }
    __syncthreads();
    if (tid < 128) {
      int gi = tid >> 1, p = tid & 1;
      float v = lacc[tid];
      if (v != 0.f) atomicAdd(&out[gi * 2 + p], v / fmaxf(counts[gi * 16], 1.f));
    }
    return;
  }
  if (tid < 128) { s_sum[tid] = 0.f; s_ssq[tid] = 0.f; }
  __syncthreads();
  int lane = tid & 63;
  int wave = __builtin_amdgcn_readfirstlane((blockIdx.x << 2) + (tid >> 6));
  int wstride = convBlks << 2;
  int c0 = lane * 2;
  float sg0 = (g[c0] >= 0.f) ? 1.f : -1.f;
  float sg1 = (g[c0 + 1] >= 0.f) ? 1.f : -1.f;
  const unsigned* A32 = (const unsigned*)A;
  const unsigned* B32 = (const unsigned*)B;
  unsigned* M32 = (unsigned*)Mx;
  float s0 = 0.f, ss0 = 0.f, s1 = 0.f, ss1 = 0.f;
  for (int n = wave; n < Nn; n += wstride) {
    int dg = deg[n];
    if (dg == 0) continue;
    int beg = rowstart[n];
    unsigned ua = A32[(size_t)n * 64 + lane];
    float a0 = blo(ua), a1 = bhi(ua);
    float mx0 = -INFINITY, mx1 = -INFINITY;
    int e = beg, eend = beg + dg;
    for (; e + 8 <= eend; e += 8) {
      int idx[8];
#pragma unroll
      for (int q = 0; q < 8; ++q) idx[q] = csr_src[e + q];
      unsigned uu[8];
#pragma unroll
      for (int q = 0; q < 8; ++q) uu[q] = B32[(size_t)idx[q] * 64 + lane];
#pragma unroll
      for (int q = 0; q < 8; ++q) {
        float m0 = a0 + blo(uu[q]), m1 = a1 + bhi(uu[q]);
        s0 += m0; ss0 += m0 * m0;
        s1 += m1; ss1 += m1 * m1;
        mx0 = fmaxf(mx0, m0);
        mx1 = fmaxf(mx1, m1);
      }
    }
    for (; e + 2 <= eend; e += 2) {
      int ia = csr_src[e], ib = csr_src[e + 1];
      unsigned u0 = B32[(size_t)ia * 64 + lane];
      unsigned u1 = B32[(size_t)ib * 64 + lane];
      float m00 = a0 + blo(u0), m01 = a1 + bhi(u0);
      float m10 = a0 + blo(u1), m11 = a1 + bhi(u1);
      s0 += m00 + m10; ss0 += m00 * m00 + m10 * m10;
      s1 += m01 + m11; ss1 += m01 * m01 + m11 * m11;
      mx0 = fmaxf(mx0, fmaxf(m00, m10));
      mx1 = fmaxf(mx1, fmaxf(m01, m11));
    }
    if (e < eend) {
      unsigned u0 = B32[(size_t)csr_src[e] * 64 + lane];
      float m00 = a0 + blo(u0), m01 = a1 + bhi(u0);
      s0 += m00; ss0 += m00 * m00;
      s1 += m01; ss1 += m01 * m01;
      mx0 = fmaxf(mx0, m00);
      mx1 = fmaxf(mx1, m01);
    }
    M32[(size_t)n * 64 + lane] = pack2(mx0, mx1);
  }
  atomicAdd(&s_sum[c0], s0 * sg0); atomicAdd(&s_ssq[c0], ss0);
  atomicAdd(&s_sum[c0 + 1], s1 * sg1); atomicAdd(&s_ssq[c0 + 1], ss1);
  __syncthreads();
  if (tid < 128) {
    float* sb = st + (size_t)(blockIdx.x & 15) * 256;
    atomicAdd(&sb[2 * tid], s_sum[tid]);
    atomicAdd(&sb[2 * tid + 1], s_ssq[tid]);
  }
}

// ---------------- DUAL conv pass (R4-proven body) + merged phase2 tail ----------------
__global__ __launch_bounds__(256, 8) void conv_pass_dual(
    const unsigned short* __restrict__ Aer, const unsigned short* __restrict__ Ber,
    const unsigned short* __restrict__ Apr, const unsigned short* __restrict__ Bpr,
    const unsigned short* __restrict__ csr_src,
    const int* __restrict__ rowstart, const int* __restrict__ deg,
    const float* __restrict__ g_er, const float* __restrict__ g_pr,
    unsigned short* __restrict__ Mer, unsigned short* __restrict__ Mpr,
    float* __restrict__ st_er, float* __restrict__ st_pr, int Nn, int convBlks,
    const float* __restrict__ zPp, const int* __restrict__ batch,
    const float* __restrict__ counts, const float* __restrict__ stpp,
    const float* __restrict__ g2, const float* __restrict__ bt2,
    float* __restrict__ out, float invN) {
  __shared__ float s_e[256], s_p[256];
  int tid = threadIdx.x;
  if ((int)blockIdx.x >= convBlks) {
    __shared__ float lacc[128];
    if (tid < 128) lacc[tid] = 0.f;
    __syncthreads();
    float m0 = stpp[0] * invN, v0 = stpp[128] * invN - m0 * m0;
    float scale0 = g2[0] * rsqrtf(v0 + EPS), shift0 = bt2[0] - m0 * scale0;
    float m1 = stpp[64] * invN, v1 = stpp[192] * invN - m1 * m1;
    float scale1 = g2[1] * rsqrtf(v1 + EPS), shift1 = bt2[1] - m1 * scale1;
    int i0 = (blockIdx.x - convBlks) * 256 + tid;
    int stride = 32 * 256;
    for (int n = i0; n < Nn; n += stride) {
      int gi = batch[n];
      atomicAdd(&lacc[gi * 2], elu_f(zPp[n * 2] * scale0 + shift0));
      atomicAdd(&lacc[gi * 2 + 1], elu_f(zPp[n * 2 + 1] * scale1 + shift1));
    }
    __syncthreads();
    if (tid < 128) {
      int gi = tid >> 1, p = tid & 1;
      float v = lacc[tid];
      if (v != 0.f) atomicAdd(&out[gi * 2 + p], v / fmaxf(counts[gi * 16], 1.f));
    }
    return;
  }
  s_e[tid] = 0.f; s_p[tid] = 0.f;
  __syncthreads();
  int lane = tid & 63;
  int wave = __builtin_amdgcn_readfirstlane((blockIdx.x << 2) + (tid >> 6));
  int wstride = convBlks << 2;
  int c0 = lane * 2;
  float sge0 = (g_er[c0] >= 0.f) ? 1.f : -1.f;
  float sge1 = (g_er[c0 + 1] >= 0.f) ? 1.f : -1.f;
  float sgp0 = (g_pr[c0] >= 0.f) ? 1.f : -1.f;
  float sgp1 = (g_pr[c0 + 1] >= 0.f) ? 1.f : -1.f;
  const unsigned* Ae32 = (const unsigned*)Aer;
  const unsigned* Be32 = (const unsigned*)Ber;
  const unsigned* Ap32 = (const unsigned*)Apr;
  const unsigned* Bp32 = (const unsigned*)Bpr;
  unsigned* Me32 = (unsigned*)Mer;
  unsigned* Mp32 = (unsigned*)Mpr;
  float se0 = 0.f, sse0 = 0.f, se1 = 0.f, sse1 = 0.f;
  float sp0 = 0.f, ssp0 = 0.f, sp1 = 0.f, ssp1 = 0.f;
  for (int n = wave; n < Nn; n += wstride) {
    int dg = deg[n];
    if (dg == 0) continue;
    int beg = rowstart[n];
    unsigned uae = Ae32[(size_t)n * 64 + lane];
    unsigned uap = Ap32[(size_t)n * 64 + lane];
    float ae0 = blo(uae), ae1 = bhi(uae);
    float ap0 = blo(uap), ap1 = bhi(uap);
    float mxe0 = -INFINITY, mxe1 = -INFINITY, mxp0 = -INFINITY, mxp1 = -INFINITY;
    int e = beg, eend = beg + dg;
    for (; e + 8 <= eend; e += 8) {
      int idx[8];
#pragma unroll
      for (int q = 0; q < 8; ++q) idx[q] = csr_src[e + q];
      unsigned ue[8], up[8];
#pragma unroll
      for (int q = 0; q < 8; ++q) ue[q] = Be32[(size_t)idx[q] * 64 + lane];
#pragma unroll
      for (int q = 0; q < 8; ++q) up[q] = Bp32[(size_t)idx[q] * 64 + lane];
#pragma unroll
      for (int q = 0; q < 8; ++q) {
        float me0 = ae0 + blo(ue[q]), me1 = ae1 + bhi(ue[q]);
        float mp0 = ap0 + blo(up[q]), mp1 = ap1 + bhi(up[q]);
        se0 += me0; sse0 += me0 * me0; se1 += me1; sse1 += me1 * me1;
        sp0 += mp0; ssp0 += mp0 * mp0; sp1 += mp1; ssp1 += mp1 * mp1;
        mxe0 = fmaxf(mxe0, me0); mxe1 = fmaxf(mxe1, me1);
        mxp0 = fmaxf(mxp0, mp0); mxp1 = fmaxf(mxp1, mp1);
      }
    }
    for (; e + 2 <= eend; e += 2) {
      int i0 = csr_src[e], i1 = csr_src[e + 1];
      unsigned ue0 = Be32[(size_t)i0 * 64 + lane];
      unsigned up0 = Bp32[(size_t)i0 * 64 + lane];
      unsigned ue1 = Be32[(size_t)i1 * 64 + lane];
      unsigned up1 = Bp32[(size_t)i1 * 64 + lane];
      float me0 = ae0 + blo(ue0), me1 = ae1 + bhi(ue0);
      float mp0 = ap0 + blo(up0), mp1 = ap1 + bhi(up0);
      float ne0 = ae0 + blo(ue1), ne1 = ae1 + bhi(ue1);
      float np0 = ap0 + blo(up1), np1 = ap1 + bhi(up1);
      se0 += me0 + ne0; sse0 += me0 * me0 + ne0 * ne0;
      se1 += me1 + ne1; sse1 += me1 * me1 + ne1 * ne1;
      sp0 += mp0 + np0; ssp0 += mp0 * mp0 + np0 * np0;
      sp1 += mp1 + np1; ssp1 += mp1 * mp1 + np1 * np1;
      mxe0 = fmaxf(mxe0, fmaxf(me0, ne0)); mxe1 = fmaxf(mxe1, fmaxf(me1, ne1));
      mxp0 = fmaxf(mxp0, fmaxf(mp0, np0)); mxp1 = fmaxf(mxp1, fmaxf(mp1, np1));
    }
    if (e < eend) {
      int i0 = csr_src[e];
      unsigned ue = Be32[(size_t)i0 * 64 + lane];
      unsigned up = Bp32[(size_t)i0 * 64 + lane];
      float me0 = ae0 + blo(ue), me1 = ae1 + bhi(ue);
      float mp0 = ap0 + blo(up), mp1 = ap1 + bhi(up);
      se0 += me0; sse0 += me0 * me0; se1 += me1; sse1 += me1 * me1;
      sp0 += mp0; ssp0 += mp0 * mp0; sp1 += mp1; ssp1 += mp1 * mp1;
      mxe0 = fmaxf(mxe0, me0); mxe1 = fmaxf(mxe1, me1);
      mxp0 = fmaxf(mxp0, mp0); mxp1 = fmaxf(mxp1, mp1);
    }
    Me32[(size_t)n * 64 + lane] = pack2(mxe0, mxe1);
    Mp32[(size_t)n * 64 + lane] = pack2(mxp0, mxp1);
  }
  atomicAdd(&s_e[2 * c0], se0 * sge0);       atomicAdd(&s_e[2 * c0 + 1], sse0);
  atomicAdd(&s_e[2 * (c0 + 1)], se1 * sge1); atomicAdd(&s_e[2 * (c0 + 1) + 1], sse1);
  atomicAdd(&s_p[2 * c0], sp0 * sgp0);       atomicAdd(&s_p[2 * c0 + 1], ssp0);
  atomicAdd(&s_p[2 * (c0 + 1)], sp1 * sgp1); atomicAdd(&s_p[2 * (c0 + 1) + 1], ssp1);
  __syncthreads();
  {
    float* se = st_er + (size_t)(blockIdx.x & 15) * 256;
    float* sp = st_pr + (size_t)(blockIdx.x & 15) * 256;
    atomicAdd(&se[tid], s_e[tid]);
    atomicAdd(&sp[tid], s_p[tid]);
  }
}

// ---------------- DUAL fused post: er + pr in one pass (terminal) ----------------
__global__ __launch_bounds__(256) void fused_post16_dual(
    const unsigned short* __restrict__ Mer, const unsigned short* __restrict__ Mpr,
    const int* __restrict__ deg,
    const float* __restrict__ st_er, const float* __restrict__ st_pr,
    const float* __restrict__ g_er, const float* __restrict__ bt_er,
    const float* __restrict__ g_pr, const float* __restrict__ bt_pr,
    const float* __restrict__ Wer, const float* __restrict__ Wpr,
    float* __restrict__ zP, float* __restrict__ stp_er, float* __restrict__ stp_pr,
    int Nn, float invE) {
  __shared__ float sce_l[128], she_l[128], scp_l[128], shp_l[128];
  __shared__ float red[4][4];
  int tid = threadIdx.x;
  if (tid < 128) {
    float sme = 0.f, sqe = 0.f, smp = 0.f, sqp = 0.f;
#pragma unroll
    for (int k = 0; k < 16; ++k) {
      sme += st_er[k * 256 + 2 * tid];
      sqe += st_er[k * 256 + 2 * tid + 1];
      smp += st_pr[k * 256 + 2 * tid];
      sqp += st_pr[k * 256 + 2 * tid + 1];
    }
    float mean = sme * invE;
    float var = sqe * invE - mean * mean;
    float sc = g_er[tid] * rsqrtf(var + EPS);
    she_l[tid] = bt_er[tid] - mean * sc;
    sce_l[tid] = (g_er[tid] < 0.f) ? -sc : sc;
    mean = smp * invE;
    var = sqp * invE - mean * mean;
    sc = g_pr[tid] * rsqrtf(var + EPS);
    shp_l[tid] = bt_pr[tid] - mean * sc;
    scp_l[tid] = (g_pr[tid] < 0.f) ? -sc : sc;
  }
  __syncthreads();
  int sub = tid & 15, c0 = sub * 8;
  float sce[8], she[8], scp[8], shp[8], we[8], wp[8];
#pragma unroll
  for (int j = 0; j < 8; ++j) {
    sce[j] = sce_l[c0 + j]; she[j] = she_l[c0 + j];
    scp[j] = scp_l[c0 + j]; shp[j] = shp_l[c0 + j];
    we[j] = Wer[c0 + j]; wp[j] = Wpr[c0 + j];
  }
  int g0 = (blockIdx.x * 256 + tid) >> 4;
  int gstride = gridDim.x * 16;
  bool leader = (sub == 0);
  float s0 = 0.f, ss0 = 0.f, s1 = 0.f, ss1 = 0.f;
  for (int n = g0; n < Nn; n += gstride) {
    float d0 = 0.f, d1 = 0.f;
    if (deg[n] > 0) {
      uint4 ve = ((const uint4*)(Mer + (size_t)n * 128))[sub];
      uint4 vp = ((const uint4*)(Mpr + (size_t)n * 128))[sub];
      unsigned wea[4] = {ve.x, ve.y, ve.z, ve.w};
      unsigned wpa[4] = {vp.x, vp.y, vp.z, vp.w};
#pragma unroll
      for (int u = 0; u < 4; ++u) {
        float te0 = blo(wea[u]) * sce[2 * u] + she[2 * u];
        float te1 = bhi(wea[u]) * sce[2 * u + 1] + she[2 * u + 1];
        float tp0 = blo(wpa[u]) * scp[2 * u] + shp[2 * u];
        float tp1 = bhi(wpa[u]) * scp[2 * u + 1] + shp[2 * u + 1];
        d0 += elu_f(te0) * we[2 * u] + elu_f(te1) * we[2 * u + 1];
        d1 += elu_f(tp0) * wp[2 * u] + elu_f(tp1) * wp[2 * u + 1];
      }
    }
#pragma unroll
    for (int off = 1; off < 16; off <<= 1) {
      d0 += __shfl_xor(d0, off);
      d1 += __shfl_xor(d1, off);
    }
    if (leader) {
      zP[n * 2] = d0;
      zP[n * 2 + 1] = d1;
      s0 += d0; ss0 += d0 * d0; s1 += d1; ss1 += d1 * d1;
    }
  }
  s0 += __shfl_xor(s0, 16);  s0 += __shfl_xor(s0, 32);
  s1 += __shfl_xor(s1, 16);  s1 += __shfl_xor(s1, 32);
  ss0 += __shfl_xor(ss0, 16); ss0 += __shfl_xor(ss0, 32);
  ss1 += __shfl_xor(ss1, 16); ss1 += __shfl_xor(ss1, 32);
  int wv = tid >> 6;
  if ((tid & 63) == 0) { red[wv][0] = s0; red[wv][1] = s1; red[wv][2] = ss0; red[wv][3] = ss1; }
  __syncthreads();
  if (tid < 4) {
    float v = red[0][tid] + red[1][tid] + red[2][tid] + red[3][tid];
    if (tid == 0) atomicAdd(&stp_er[0], v);
    else if (tid == 1) atomicAdd(&stp_pr[0], v);
    else if (tid == 2) atomicAdd(&stp_er[128], v);
    else atomicAdd(&stp_pr[128], v);
  }
}

// dual terminal: col0 <- er, col1 <- pr
__global__ __launch_bounds__(256) void post_phase2_dual(const float* __restrict__ zP,
    const int* __restrict__ batch, const float* __restrict__ counts,
    const float* __restrict__ st_er, const float* __restrict__ st_pr,
    const float* __restrict__ g_er, const float* __restrict__ bt_er,
    const float* __restrict__ g_pr, const float* __restrict__ bt_pr,
    float* __restrict__ out, int Nrows, float invN) {
  __shared__ float lacc[128];
  if (threadIdx.x < 128) lacc[threadIdx.x] = 0.f;
  __syncthreads();
  float m0 = st_er[0] * invN;
  float v0 = st_er[128] * invN - m0 * m0;
  float scale0 = g_er[0] * rsqrtf(v0 + EPS);
  float shift0 = bt_er[0] - m0 * scale0;
  float m1 = st_pr[0] * invN;
  float v1 = st_pr[128] * invN - m1 * m1;
  float scale1 = g_pr[0] * rsqrtf(v1 + EPS);
  float shift1 = bt_pr[0] - m1 * scale1;
  int i0 = blockIdx.x * 256 + threadIdx.x;
  int stride = gridDim.x * 256;
  for (int n = i0; n < Nrows; n += stride) {
    int gi = batch[n];
    float y0 = elu_f(zP[n * 2] * scale0 + shift0);
    float y1 = elu_f(zP[n * 2 + 1] * scale1 + shift1);
    atomicAdd(&lacc[gi * 2], y0);
    atomicAdd(&lacc[gi * 2 + 1], y1);
  }
  __syncthreads();
  if (threadIdx.x < 128) {
    int gi = threadIdx.x >> 1, p = threadIdx.x & 1;
    float v = lacc[threadIdx.x];
    if (v != 0.f)
      atomicAdd(&out[gi * 2 + p], v / fmaxf(counts[gi * 16], 1.f));
  }
}

extern "C" void kernel_launch(void* const* d_in, const int* in_sizes, int n_in,
                              void* d_out, int out_size, void* d_ws, size_t ws_size,
                              hipStream_t stream) {
  const float* x       = (const float*)d_in[0];
  const int*   ei      = (const int*)d_in[1];
  const int*   batch   = (const int*)d_in[2];
  const float* init_W  = (const float*)d_in[3];
  const float* init_g  = (const float*)d_in[5];
  const float* init_bt = (const float*)d_in[6];
  const float* mid_W   = (const float*)d_in[7];
  const float* mid_g   = (const float*)d_in[9];
  const float* mid_bt  = (const float*)d_in[10];
  const float* er_W    = (const float*)d_in[11];
  const float* er_g    = (const float*)d_in[13];
  const float* er_bt   = (const float*)d_in[14];
  const float* pr_W    = (const float*)d_in[15];
  const float* pr_g    = (const float*)d_in[17];
  const float* pr_bt   = (const float*)d_in[18];
  const float* spost_W  = (const float*)d_in[19];
  const float* spost_g  = (const float*)d_in[21];
  const float* spost_bt = (const float*)d_in[22];
  const float* erpost_W  = (const float*)d_in[23];
  const float* erpost_g  = (const float*)d_in[25];
  const float* erpost_bt = (const float*)d_in[26];
  const float* prpost_W  = (const float*)d_in[27];
  const float* prpost_g  = (const float*)d_in[29];
  const float* prpost_bt = (const float*)d_in[30];

  int N = in_sizes[0] / 128;
  int E = in_sizes[1] / 2;
  float invN = 1.f / (float)N;
  float invE = 1.f / (float)E;
  float* out = (float*)d_out;

  const int CONV_BLKS = 2048;
  int nbuck = (N + 255) >> 8;
  int p1b = (E + P1_CHUNK - 1) / P1_CHUNK;

  size_t NB = (size_t)N * 128;
  unsigned short* TbI = (unsigned short*)d_ws;
  unsigned short* Tb0 = TbI + NB;
  unsigned short* Tb1 = Tb0 + NB;
  unsigned short* Tb2 = Tb1 + NB;
  unsigned short* Tb3 = Tb2 + NB;
  unsigned short* MxB = Tb3 + NB;
  unsigned short* MxB2 = MxB + NB;
  float* zP     = (float*)(MxB2 + NB);
  float* counts = zP + (size_t)2 * N;
  float* stats  = counts + 1024;               // 5 slots x (16 copies x 256) node stats
  float* post   = stats + 5 * 4096;            // 5 slots x 512 post stats
  unsigned short* WT = (unsigned short*)(post + 5 * 512);  // 9 x 16384
  int* deg        = (int*)(WT + 9 * 16384);
  int* rowstart   = deg + N;
  int* bucketbase = rowstart + N;              // 257 (pad 320)
  int* gcursor    = bucketbase + 320;          // 256 x 16 (padded)
  int* partials   = gcursor + 256 * 16;        // 64 x 256
  unsigned* binned = (unsigned*)(partials + 64 * 256);   // E
  unsigned short* csr_src = (unsigned short*)(binned + E); // E (ushort)

  int gemmGrid = (N + 63) / 64;

  hipMemsetAsync(d_out, 0, out_size * sizeof(float), stream);
  hipMemsetAsync(counts, 0, (1024 + 5 * 4096 + 5 * 512) * sizeof(float), stream);

  // weight prep + CSR p0 count/hist merged
  const int* e_src = ei;
  const int* e_dst = ei + E;
  prep_csr0<<<448, 256, 0, stream>>>(init_W, mid_W, er_W, pr_W, mid_g, er_g, pr_g, WT,
                                     e_dst, partials, E, batch, counts, N);
  csr_p0_scan<<<1, 256, 0, stream>>>(partials, 64, bucketbase, gcursor);

  // ---- merged: CSR p1 bin + init GEMM (fp32 x -> TbI, node stats fused) ----
  p1_initgemm<<<p1b + gemmGrid, 256, 0, stream>>>(e_src, e_dst, gcursor, binned, E, p1b,
      (const void*)x, WT, TbI, stats, N);

  // ---- merged: CSR p2 sort + mid0 ACT-GEMM (gelu(BN(TbI)) -> Tb0,Tb1; init zP/stp fused) ----
  p2_act0<<<nbuck + gemmGrid, 256, 0, stream>>>(binned, bucketbase, csr_src, deg, rowstart,
      N, nbuck, TbI, WT + 1 * 16384, WT + 2 * 16384, Tb0, Tb1,
      stats, init_g, init_bt, spost_W, zP, post + 0 * 512, invN);

  // ---- conv0 -> MxB + stats1; tail finishes init-layer phase2 ----
  conv_pass<<<CONV_BLKS + 32, 256, 0, stream>>>(Tb0, Tb1, csr_src, rowstart, deg, mid_g,
      MxB, stats + 1 * 4096, N, CONV_BLKS,
      zP, batch, counts, post + 0 * 512, spost_g, spost_bt, out, invN);

  // ---- mid1 ACT-GEMM: elu(BN(MxB)) -> Tb0,Tb1 ; mid0 zP + post stats fused ----
  gemm_act<2, 2><<<gemmGrid, 256, 0, stream>>>(MxB,
      WT + 3 * 16384, WT + 4 * 16384, nullptr, nullptr, Tb0, Tb1, nullptr, nullptr,
      stats + 1 * 4096, mid_g, mid_bt, deg, spost_W + 256, zP, post + 1 * 512, invE, N);

  // ---- conv1 -> MxB + stats2; tail finishes mid0 phase2 ----
  conv_pass<<<CONV_BLKS + 32, 256, 0, stream>>>(Tb0, Tb1, csr_src, rowstart, deg, mid_g + 128,
      MxB, stats + 2 * 4096, N, CONV_BLKS,
      zP, batch, counts, post + 1 * 512, spost_g + 2, spost_bt + 2, out, invN);

  // ---- er/pr ACT-GEMM: elu(BN(MxB)) -> Tb0..Tb3 ; mid1 zP + post stats fused ----
  gemm_act<4, 2><<<gemmGrid, 256, 0, stream>>>(MxB,
      WT + 5 * 16384, WT + 6 * 16384, WT + 7 * 16384, WT + 8 * 16384,
      Tb0, Tb1, Tb2, Tb3,
      stats + 2 * 4096, mid_g + 128, mid_bt + 128, deg, spost_W + 512,
      zP, post + 2 * 512, invE, N);

  // ---- dual conv -> MxB, MxB2 + stats3/4; tail finishes mid1 phase2 ----
  conv_pass_dual<<<CONV_BLKS + 32, 256, 0, stream>>>(Tb0, Tb1, Tb2, Tb3, csr_src, rowstart, deg,
      er_g, pr_g, MxB, MxB2, stats + 3 * 4096, stats + 4 * 4096, N, CONV_BLKS,
      zP, batch, counts, post + 2 * 512, spost_g + 4, spost_bt + 4, out, invN);

  // ---- terminal er/pr posts ----
  fused_post16_dual<<<512, 256, 0, stream>>>(MxB, MxB2, deg,
      stats + 3 * 4096, stats + 4 * 4096, er_g, er_bt, pr_g, pr_bt,
      erpost_W, prpost_W, zP, post + 3 * 512, post + 4 * 512, N, invE);
  post_phase2_dual<<<32, 256, 0, stream>>>(zP, batch, counts,
      post + 3 * 512, post + 4 * 512, erpost_g, erpost_bt, prpost_g, prpost_bt,
      out, N, invN);
}